// Round 13
// baseline (365.533 us; speedup 1.0000x reference)
//
#include <hip/hip_runtime.h>
#include <math.h>

#define NN 32000
#define NE 320000
#define NG 1600
#define LOG2E 1.4426950408889634f
#define LN2   0.6931471805599453f

using frag_ab = __attribute__((ext_vector_type(8))) short;   // 8 bf16 (4 VGPRs)
using frag_cd = __attribute__((ext_vector_type(4))) float;   // 4 fp32
typedef float v2f __attribute__((ext_vector_type(2)));

static __device__ __forceinline__ unsigned short f2bf(float f) {
  unsigned u = __builtin_bit_cast(unsigned, f);
  unsigned r = u + 0x7fff + ((u >> 16) & 1);   // RNE
  return (unsigned short)(r >> 16);
}
static __device__ __forceinline__ float bflo(unsigned u) {
  return __builtin_bit_cast(float, u << 16);
}
static __device__ __forceinline__ float bfhi(unsigned u) {
  return __builtin_bit_cast(float, u & 0xffff0000u);
}
static __device__ __forceinline__ float bfs(unsigned short u) {
  return __builtin_bit_cast(float, (unsigned)u << 16);
}
static __device__ __forceinline__ v2f unpk(unsigned u) {
  return (v2f){bflo(u), bfhi(u)};
}

// Fused: embed->hb (+accumb zero) | prep_we (FRAGMENT-ordered) | prep_wg.
// Weights prescaled by log2e.
__global__ __launch_bounds__(256) void k_misc(const int* __restrict__ x,
                                              const float* __restrict__ emb,
                                              const float* __restrict__ Wf1, const float* __restrict__ Ws1,
                                              const float* __restrict__ Wf2, const float* __restrict__ Ws2,
                                              const float* __restrict__ Wf3, const float* __restrict__ Ws3,
                                              unsigned short* __restrict__ hb,
                                              unsigned short* __restrict__ accumb,
                                              unsigned short* __restrict__ wedge,
                                              unsigned short* __restrict__ wgemm) {
  int b = blockIdx.x;
  int tid = threadIdx.x;
  if (b < 2000) {
    int idx = b * 256 + tid;   // 512000 = 32000*16
    int n = idx >> 4;
    int c8 = (idx & 15) << 3;
    const float* e = emb + (size_t)x[n] * 128 + c8;
    float4 v0 = *(const float4*)e;
    float4 v1 = *(const float4*)(e + 4);
    ushort4 p0, p1;
    p0.x = f2bf(v0.x); p0.y = f2bf(v0.y); p0.z = f2bf(v0.z); p0.w = f2bf(v0.w);
    p1.x = f2bf(v1.x); p1.y = f2bf(v1.y); p1.z = f2bf(v1.z); p1.w = f2bf(v1.w);
    unsigned short* hbp = hb + (size_t)n * 128 + c8;
    *(ushort4*)hbp = p0;
    *(ushort4*)(hbp + 4) = p1;
    *(uint4*)(accumb + (size_t)n * 128 + c8) = make_uint4(0, 0, 0, 0);
  } else if (b < 2096) {
    // wedge fragment-ordered (x log2e): r = ((w*4+t)*64 + lane)*8 + j
    // stores B(col = w*64 + t*16 + (lane&15), k = (lane>>4)*8 + j);
    // channel = w*32 + 2*(lane&15) + (t&1); t<2 -> Wf else Ws
    int idx = (b - 2000) * 256 + tid;    // 3*8192
    int l = idx >> 13;
    int r = idx & 8191;
    int j = r & 7;
    int lane = (r >> 3) & 63;
    int wt = r >> 9;                     // 0..15
    int w = wt >> 2, t = wt & 3;
    int c = lane & 15, q = lane >> 4;
    int k = q * 8 + j;
    const float* Wf = (l == 0) ? Wf1 : (l == 1) ? Wf2 : Wf3;
    const float* Ws = (l == 0) ? Ws1 : (l == 1) ? Ws2 : Ws3;
    const float* W = (t < 2) ? Wf : Ws;
    int ch = w * 32 + 2 * c + (t & 1);
    wedge[(size_t)l * 8192 + r] = f2bf(W[(size_t)(256 + k) * 128 + ch] * LOG2E);
  } else {
    // wgemm (x log2e): col cc -> T position p = (cc&~31) + 2*(cc&15) + ((cc>>4)&1).
    int idx = (b - 2096) * 256 + tid;    // 3*65536
    int l = idx >> 16;
    int r = idx & 65535;
    int cc = r >> 7;
    int k = r & 127;
    int p = (cc & ~31) + ((cc & 15) << 1) + ((cc >> 4) & 1);
    int ph = p & 255;
    int j = ph >> 2, sub = ph & 3;
    const float* Wf = (l == 0) ? Wf1 : (l == 1) ? Wf2 : Wf3;
    const float* Ws = (l == 0) ? Ws1 : (l == 1) ? Ws2 : Ws3;
    const float* W = (sub < 2) ? Wf : Ws;
    int ch = 2 * j + (sub & 1);
    int krow = ((p < 256) ? 0 : 128) + k;
    wgemm[(size_t)l * 65536 + cc * 128 + k] = f2bf(W[(size_t)krow * 128 + ch] * LOG2E);
  }
}

// Fused: hist (blocks 0..1249) | bstarts (blocks 1250..1375)
__global__ __launch_bounds__(256) void k_histb(const int* __restrict__ ei,
                                               const int* __restrict__ batch,
                                               int* __restrict__ counts,
                                               int* __restrict__ starts) {
  int b = blockIdx.x;
  int tid = threadIdx.x;
  if (b < 1250) {
    int e = b * 256 + tid;
    atomicAdd(counts + ei[NE + e], 1);
  } else {
    int n = (b - 1250) * 256 + tid;
    if (n > NN) return;
    if (n == NN) {
      starts[NG] = NN;
      int last = batch[NN - 1];
      for (int g = last + 1; g < NG; ++g) starts[g] = NN;
    } else if (n == 0) {
      int bb = batch[0];
      for (int g = 0; g <= bb; ++g) starts[g] = 0;
    } else {
      int b0 = batch[n - 1], b1 = batch[n];
      for (int g = b0 + 1; g <= b1; ++g) starts[g] = n;
    }
  }
}

// exclusive prefix sum of counts[32000] -> offs
__global__ __launch_bounds__(1024) void k_scan(const int* __restrict__ counts,
                                               int* __restrict__ offs) {
  __shared__ int part[1024];
  __shared__ int carry_s;
  int t = threadIdx.x;
  if (t == 0) carry_s = 0;
  __syncthreads();
  for (int chunk = 0; chunk < 4; ++chunk) {
    int base = chunk * 8192 + t * 8;
    int4 a = make_int4(0, 0, 0, 0), bq = make_int4(0, 0, 0, 0);
    bool full = (base + 8 <= NN);
    if (full) {
      a = *(const int4*)(counts + base);
      bq = *(const int4*)(counts + base + 4);
    }
    int e1 = a.x, e2 = e1 + a.y, e3 = e2 + a.z, e4 = e3 + a.w;
    int e5 = e4 + bq.x, e6 = e5 + bq.y, e7 = e6 + bq.z;
    int run = e7 + bq.w;
    part[t] = run;
    __syncthreads();
    for (int off = 1; off < 1024; off <<= 1) {
      int v = (t >= off) ? part[t - off] : 0;
      __syncthreads();
      part[t] += v;
      __syncthreads();
    }
    int excl = carry_s + ((t == 0) ? 0 : part[t - 1]);
    if (full) {
      int4 o0 = make_int4(excl, excl + e1, excl + e2, excl + e3);
      int4 o1 = make_int4(excl + e4, excl + e5, excl + e6, excl + e7);
      *(int4*)(offs + base) = o0;
      *(int4*)(offs + base + 4) = o1;
    }
    __syncthreads();
    if (t == 0) carry_s += part[1023];
    __syncthreads();
  }
}

// scatter pass 1: perm[pos] = original edge index
__global__ __launch_bounds__(256) void k_scat1(const int* __restrict__ ei,
                                               int* __restrict__ offs,
                                               int* __restrict__ perm) {
  int e = blockIdx.x * 256 + threadIdx.x;
  int d = ei[NE + e];
  int pos = atomicAdd(offs + d, 1);
  perm[pos] = e;
}

// Merged dispatch: blocks 0..1999 = layer-1 GEMM; blocks 2000..6999 = scatter pass 2.
__global__ __launch_bounds__(256) void k_s2g(const unsigned short* __restrict__ hb,
                                             const unsigned short* __restrict__ wgemmL,
                                             unsigned short* __restrict__ T,
                                             const int* __restrict__ ei,
                                             const float* __restrict__ ea,
                                             const int* __restrict__ perm,
                                             int* __restrict__ srcp,
                                             int* __restrict__ dstp,
                                             unsigned short* __restrict__ eab) {
  __shared__ short sA[64 * 136];
  __shared__ short sB[128 * 136];
  __shared__ int se[64];
  int b = blockIdx.x;
  int tid = threadIdx.x;
  if (b < 2000) {
    int m0 = (b >> 2) * 64;
    int n0 = (b & 3) * 128;
#pragma unroll
    for (int i = 0; i < 4; ++i) {
      int idx = tid + i * 256;
      int row = idx >> 4, chk = idx & 15;
      uint4 v = *(const uint4*)(hb + (size_t)(m0 + row) * 128 + chk * 8);
      *(uint4*)&sA[row * 136 + chk * 8] = v;
    }
#pragma unroll
    for (int i = 0; i < 8; ++i) {
      int idx = tid + i * 256;
      int col = idx >> 4, chk = idx & 15;
      uint4 v = *(const uint4*)(wgemmL + (size_t)(n0 + col) * 128 + chk * 8);
      *(uint4*)&sB[col * 136 + chk * 8] = v;
    }
    __syncthreads();
    int w = tid >> 6, lane = tid & 63, c = lane & 15, q = lane >> 4;
    frag_cd acc[4][2];
#pragma unroll
    for (int mt = 0; mt < 4; ++mt)
#pragma unroll
      for (int t = 0; t < 2; ++t) acc[mt][t] = (frag_cd){0.f, 0.f, 0.f, 0.f};
#pragma unroll
    for (int ks = 0; ks < 4; ++ks) {
      frag_ab Af[4], Bf[2];
#pragma unroll
      for (int mt = 0; mt < 4; ++mt)
        Af[mt] = *(const frag_ab*)&sA[(mt * 16 + c) * 136 + ks * 32 + q * 8];
#pragma unroll
      for (int t = 0; t < 2; ++t)
        Bf[t] = *(const frag_ab*)&sB[(w * 32 + t * 16 + c) * 136 + ks * 32 + q * 8];
#pragma unroll
      for (int mt = 0; mt < 4; ++mt)
#pragma unroll
        for (int t = 0; t < 2; ++t)
          acc[mt][t] = __builtin_amdgcn_mfma_f32_16x16x32_bf16(Af[mt], Bf[t], acc[mt][t], 0, 0, 0);
    }
    int nbase = n0 + w * 32 + 2 * c;
#pragma unroll
    for (int mt = 0; mt < 4; ++mt) {
#pragma unroll
      for (int r = 0; r < 4; ++r) {
        int node = m0 + mt * 16 + q * 4 + r;
        unsigned pk = (unsigned)f2bf(acc[mt][0][r]) | ((unsigned)f2bf(acc[mt][1][r]) << 16);
        *(unsigned*)(T + (size_t)node * 512 + nbase) = pk;
      }
    }
  } else {
    int base = (b - 2000) * 64;
    if (tid < 64) {
      int e = perm[base + tid];
      se[tid] = e;
      srcp[base + tid] = ei[e];
      dstp[base + tid] = ei[NE + e];
    }
    __syncthreads();
    int x = tid >> 2;
    int ck = tid & 3;
    int e = se[x];
    const float* a = ea + (size_t)e * 32 + ck * 8;
    float4 v0 = *(const float4*)a;
    float4 v1 = *(const float4*)(a + 4);
    int p = (((x >> 2) & 3) << 4) | ((x >> 4) << 2) | (x & 3);
    unsigned short* q = eab + (size_t)(base + p) * 32 + ck * 8;
    ushort4 o0, o1;
    o0.x = f2bf(v0.x); o0.y = f2bf(v0.y); o0.z = f2bf(v0.z); o0.w = f2bf(v0.w);
    o1.x = f2bf(v1.x); o1.y = f2bf(v1.y); o1.z = f2bf(v1.z); o1.w = f2bf(v1.w);
    *(ushort4*)q = o0;
    *(ushort4*)(q + 4) = o1;
  }
}

// Fused update + GEMM (layers 2,3): block owns 64 rows exclusively.
// hb <- relu(hb + accumb) (bf16, also staged to sA); accumb <- 0;
// T[rows][512] = updated-hb @ wgemmL, looping all 4 column panels.
__global__ __launch_bounds__(256) void k_ugemm(unsigned short* __restrict__ hb,
                                               unsigned short* __restrict__ accumb,
                                               const unsigned short* __restrict__ wgemmL,
                                               unsigned short* __restrict__ T) {
  __shared__ short sA[64 * 136];
  __shared__ short sB[128 * 136];
  int m0 = blockIdx.x * 64;
  int tid = threadIdx.x;
#pragma unroll
  for (int i = 0; i < 4; ++i) {
    int idx = tid + i * 256;
    int row = idx >> 4, chk = idx & 15;
    size_t off = (size_t)(m0 + row) * 128 + chk * 8;
    uint4 a = *(uint4*)(accumb + off);
    uint4 hv = *(uint4*)(hb + off);
    float r0 = fmaxf(bflo(hv.x) + bflo(a.x), 0.f);
    float r1 = fmaxf(bfhi(hv.x) + bfhi(a.x), 0.f);
    float r2 = fmaxf(bflo(hv.y) + bflo(a.y), 0.f);
    float r3 = fmaxf(bfhi(hv.y) + bfhi(a.y), 0.f);
    float r4 = fmaxf(bflo(hv.z) + bflo(a.z), 0.f);
    float r5 = fmaxf(bfhi(hv.z) + bfhi(a.z), 0.f);
    float r6 = fmaxf(bflo(hv.w) + bflo(a.w), 0.f);
    float r7 = fmaxf(bfhi(hv.w) + bfhi(a.w), 0.f);
    uint4 o;
    o.x = (unsigned)f2bf(r0) | ((unsigned)f2bf(r1) << 16);
    o.y = (unsigned)f2bf(r2) | ((unsigned)f2bf(r3) << 16);
    o.z = (unsigned)f2bf(r4) | ((unsigned)f2bf(r5) << 16);
    o.w = (unsigned)f2bf(r6) | ((unsigned)f2bf(r7) << 16);
    *(uint4*)(hb + off) = o;
    *(uint4*)(accumb + off) = make_uint4(0, 0, 0, 0);
    *(uint4*)&sA[row * 136 + chk * 8] = o;
  }
  int w = tid >> 6, lane = tid & 63, c = lane & 15, q = lane >> 4;
#pragma unroll 1
  for (int nb = 0; nb < 4; ++nb) {
    int n0 = nb * 128;
    __syncthreads();   // sA ready (nb=0) / previous panel's readers done (nb>0)
#pragma unroll
    for (int i = 0; i < 8; ++i) {
      int idx = tid + i * 256;
      int col = idx >> 4, chk = idx & 15;
      uint4 v = *(const uint4*)(wgemmL + (size_t)(n0 + col) * 128 + chk * 8);
      *(uint4*)&sB[col * 136 + chk * 8] = v;
    }
    __syncthreads();
    frag_cd acc[4][2];
#pragma unroll
    for (int mt = 0; mt < 4; ++mt)
#pragma unroll
      for (int t = 0; t < 2; ++t) acc[mt][t] = (frag_cd){0.f, 0.f, 0.f, 0.f};
#pragma unroll
    for (int ks = 0; ks < 4; ++ks) {
      frag_ab Af[4], Bf[2];
#pragma unroll
      for (int mt = 0; mt < 4; ++mt)
        Af[mt] = *(const frag_ab*)&sA[(mt * 16 + c) * 136 + ks * 32 + q * 8];
#pragma unroll
      for (int t = 0; t < 2; ++t)
        Bf[t] = *(const frag_ab*)&sB[(w * 32 + t * 16 + c) * 136 + ks * 32 + q * 8];
#pragma unroll
      for (int mt = 0; mt < 4; ++mt)
#pragma unroll
        for (int t = 0; t < 2; ++t)
          acc[mt][t] = __builtin_amdgcn_mfma_f32_16x16x32_bf16(Af[mt], Bf[t], acc[mt][t], 0, 0, 0);
    }
    int nbase = n0 + w * 32 + 2 * c;
#pragma unroll
    for (int mt = 0; mt < 4; ++mt) {
#pragma unroll
      for (int r = 0; r < 4; ++r) {
        int node = m0 + mt * 16 + q * 4 + r;
        unsigned pk = (unsigned)f2bf(acc[mt][0][r]) | ((unsigned)f2bf(acc[mt][1][r]) << 16);
        *(unsigned*)(T + (size_t)node * 512 + nbase) = pk;
      }
    }
  }
}

// Per-edge MFMA + dwordx2 gathers + register run-merge + packed bf16 atomics.
// B-fragments loaded directly from fragment-ordered wedge (L2 broadcast, no LDS).
__global__ __launch_bounds__(256) void k_edge(const int* __restrict__ srcp,
                                              const int* __restrict__ dstp,
                                              const unsigned short* __restrict__ eab,
                                              const unsigned short* __restrict__ T,
                                              const unsigned short* __restrict__ wedgeL,
                                              const float* __restrict__ bf,
                                              const float* __restrict__ bs,
                                              unsigned short* __restrict__ accumb) {
  __shared__ short sA[64 * 40];
  __shared__ float sbf[128], sbs[128];
  __shared__ int sSrc[64], sDst[64];
  int tid = threadIdx.x;
  int e0 = blockIdx.x * 64;

  int w = tid >> 6;
  int lane = tid & 63;
  int c = lane & 15;
  int q = lane >> 4;

  // B fragments: coalesced dwordx4 from fragment-ordered wedge (16KB, L2-resident)
  frag_ab Bf[4];
#pragma unroll
  for (int t = 0; t < 4; ++t)
    Bf[t] = *(const frag_ab*)(wedgeL + (((w * 4 + t) * 64 + lane) << 3));

  {
    int row = tid >> 2, qq = tid & 3;
    uint4 v = *(const uint4*)(eab + (size_t)e0 * 32 + tid * 8);
    *(uint4*)&sA[row * 40 + qq * 8] = v;
  }
  if (tid < 128) {
    sbf[tid] = bf[tid] * LOG2E;
    sbs[tid] = bs[tid] * LOG2E;
  } else if (tid < 192) {
    sSrc[tid - 128] = srcp[e0 + tid - 128] * 512 + 256;
  } else {
    sDst[tid - 192] = dstp[e0 + tid - 192] * 512;
  }
  __syncthreads();

  frag_ab Af[4];
#pragma unroll
  for (int et = 0; et < 4; ++et)
    Af[et] = *(const frag_ab*)&sA[(et * 16 + c) * 40 + q * 8];

  frag_cd acc[4][4];
#pragma unroll
  for (int et = 0; et < 4; ++et)
#pragma unroll
    for (int t = 0; t < 4; ++t)
      acc[et][t] = (frag_cd){0.f, 0.f, 0.f, 0.f};
#pragma unroll
  for (int et = 0; et < 4; ++et)
#pragma unroll
    for (int t = 0; t < 4; ++t)
      acc[et][t] = __builtin_amdgcn_mfma_f32_16x16x32_bf16(Af[et], Bf[t], acc[et][t], 0, 0, 0);

  int ch = w * 32 + 2 * c;
  int jo = ch * 2;
  v2f bfv = {sbf[ch], sbf[ch + 1]};
  v2f bsv = {sbs[ch], sbs[ch + 1]};

  int prevd = sDst[q * 16];
  v2f av = {0.f, 0.f};
#pragma unroll
  for (int grp = 0; grp < 2; ++grp) {
    uint2 dv[8], sv[8];
#pragma unroll
    for (int i = 0; i < 8; ++i) {
      int e = q * 16 + grp * 8 + i;
      dv[i] = *(const uint2*)(T + sDst[e] + jo);
      sv[i] = *(const uint2*)(T + sSrc[e] + jo);
    }
    v2f m[8];
#pragma unroll
    for (int i = 0; i < 8; ++i) {
      int idx = grp * 8 + i;
      int et = idx >> 2, r = idx & 3;
      v2f xf = (v2f){acc[et][0][r], acc[et][1][r]} + unpk(dv[i].x) + unpk(sv[i].x) + bfv;
      v2f xs = (v2f){acc[et][2][r], acc[et][3][r]} + unpk(dv[i].y) + unpk(sv[i].y) + bsv;
      float g0 = __builtin_amdgcn_rcpf(1.f + __builtin_amdgcn_exp2f(-xf.x));
      float g1 = __builtin_amdgcn_rcpf(1.f + __builtin_amdgcn_exp2f(-xf.y));
      float sp0 = fmaxf(xs.x, 0.f) + __builtin_amdgcn_logf(1.f + __builtin_amdgcn_exp2f(-fabsf(xs.x)));
      float sp1 = fmaxf(xs.y, 0.f) + __builtin_amdgcn_logf(1.f + __builtin_amdgcn_exp2f(-fabsf(xs.y)));
      m[i] = (v2f){g0 * sp0, g1 * sp1};
    }
#pragma unroll
    for (int i = 0; i < 8; ++i) {
      int d = sDst[q * 16 + grp * 8 + i];
      if (d != prevd) {
        v2f o = av * LN2;
        unsigned pk = (unsigned)f2bf(o.x) | ((unsigned)f2bf(o.y) << 16);
        unsigned short* p = accumb + (size_t)(prevd >> 2) + ch;
        asm volatile("global_atomic_pk_add_bf16 %0, %1, off" :: "v"(p), "v"(pk) : "memory");
        av = (v2f){0.f, 0.f};
        prevd = d;
      }
      av += m[i];
    }
  }
  {
    v2f o = av * LN2;
    unsigned pk = (unsigned)f2bf(o.x) | ((unsigned)f2bf(o.y) << 16);
    unsigned short* p = accumb + (size_t)(prevd >> 2) + ch;
    asm volatile("global_atomic_pk_add_bf16 %0, %1, off" :: "v"(p), "v"(pk) : "memory");
  }
}

// Fused layer-3 update + segmented mean-pool + final matmul
__global__ __launch_bounds__(128) void k_pool_final(const unsigned short* __restrict__ hb,
                                                    const unsigned short* __restrict__ accumb,
                                                    const int* __restrict__ starts,
                                                    const float* __restrict__ Wlin,
                                                    const float* __restrict__ blin,
                                                    float* __restrict__ out) {
  __shared__ float p[128];
  int g = blockIdx.x, c = threadIdx.x;
  int s0 = starts[g], s1 = starts[g + 1];
  float acc = 0.f;
  for (int n = s0; n < s1; ++n) {
    float hv = bfs(hb[(size_t)n * 128 + c]);
    float av = bfs(accumb[(size_t)n * 128 + c]);
    acc += fmaxf(hv + av, 0.f);
  }
  float inv = 1.f / fmaxf((float)(s1 - s0), 1.f);
  p[c] = acc * inv;
  __syncthreads();
  float o = blin[c];
#pragma unroll 8
  for (int k = 0; k < 128; ++k) o += p[k] * Wlin[k * 128 + c];
  out[(size_t)g * 128 + c] = o;
}

extern "C" void kernel_launch(void* const* d_in, const int* in_sizes, int n_in,
                              void* d_out, int out_size, void* d_ws, size_t ws_size,
                              hipStream_t stream) {
  const int* x = (const int*)d_in[0];
  const int* ei = (const int*)d_in[1];
  const float* ea = (const float*)d_in[2];
  const int* batch = (const int*)d_in[3];
  const float* emb = (const float*)d_in[4];
  const float* Wf[3] = {(const float*)d_in[5], (const float*)d_in[9], (const float*)d_in[13]};
  const float* bf[3] = {(const float*)d_in[6], (const float*)d_in[10], (const float*)d_in[14]};
  const float* Wsm[3] = {(const float*)d_in[7], (const float*)d_in[11], (const float*)d_in[15]};
  const float* bs[3] = {(const float*)d_in[8], (const float*)d_in[12], (const float*)d_in[16]};
  const float* Wlin = (const float*)d_in[17];
  const float* blin = (const float*)d_in[18];
  float* out = (float*)d_out;

  char* ws = (char*)d_ws;
  unsigned short* hb = (unsigned short*)ws;     ws += (size_t)NN * 128 * 2;
  unsigned short* accumb = (unsigned short*)ws; ws += (size_t)NN * 128 * 2;
  unsigned short* T = (unsigned short*)ws;      ws += (size_t)NN * 512 * 2;
  unsigned short* eab = (unsigned short*)ws;    ws += (size_t)NE * 32 * 2;
  unsigned short* wedge = (unsigned short*)ws;  ws += 3 * 8192 * 2;
  unsigned short* wgemm = (unsigned short*)ws;  ws += 3 * 65536 * 2;
  int* counts = (int*)ws;                       ws += (size_t)NN * 4;   // zeroed
  int* offs = (int*)ws;                         ws += (size_t)NN * 4;
  int* srcp = (int*)ws;                         ws += (size_t)NE * 4;
  int* dstp = (int*)ws;                         ws += (size_t)NE * 4;
  int* perm = (int*)ws;                         ws += (size_t)NE * 4;
  int* starts = (int*)ws;                       ws += (size_t)(NG + 1) * 4;

  hipMemsetAsync(counts, 0, (size_t)NN * 4, stream);
  k_misc<<<2864, 256, 0, stream>>>(x, emb, Wf[0], Wsm[0], Wf[1], Wsm[1], Wf[2], Wsm[2],
                                   hb, accumb, wedge, wgemm);
  k_histb<<<1376, 256, 0, stream>>>(ei, batch, counts, starts);
  k_scan<<<1, 1024, 0, stream>>>(counts, offs);
  k_scat1<<<1250, 256, 0, stream>>>(ei, offs, perm);
  k_s2g<<<7000, 256, 0, stream>>>(hb, wgemm, T, ei, ea, perm, srcp, dstp, eab);
  for (int l = 0; l < 3; ++l) {
    if (l > 0)
      k_ugemm<<<500, 256, 0, stream>>>(hb, accumb, wgemm + (size_t)l * 65536, T);
    k_edge<<<5000, 256, 0, stream>>>(srcp, dstp, eab, T, wedge + (size_t)l * 8192,
                                     bf[l], bs[l], accumb);
  }
  k_pool_final<<<1600, 128, 0, stream>>>(hb, accumb, starts, Wlin, blin, out);
}

// Round 14
// 351.187 us; speedup vs baseline: 1.0409x; 1.0409x over previous
//
#include <hip/hip_runtime.h>
#include <math.h>

#define NN 32000
#define NE 320000
#define NG 1600
#define LOG2E 1.4426950408889634f
#define LN2   0.6931471805599453f

using frag_ab = __attribute__((ext_vector_type(8))) short;   // 8 bf16 (4 VGPRs)
using frag_cd = __attribute__((ext_vector_type(4))) float;   // 4 fp32
typedef float v2f __attribute__((ext_vector_type(2)));

static __device__ __forceinline__ unsigned short f2bf(float f) {
  unsigned u = __builtin_bit_cast(unsigned, f);
  unsigned r = u + 0x7fff + ((u >> 16) & 1);   // RNE
  return (unsigned short)(r >> 16);
}
static __device__ __forceinline__ float bflo(unsigned u) {
  return __builtin_bit_cast(float, u << 16);
}
static __device__ __forceinline__ float bfhi(unsigned u) {
  return __builtin_bit_cast(float, u & 0xffff0000u);
}
static __device__ __forceinline__ float bfs(unsigned short u) {
  return __builtin_bit_cast(float, (unsigned)u << 16);
}
static __device__ __forceinline__ v2f unpk(unsigned u) {
  return (v2f){bflo(u), bfhi(u)};
}

// Fused: embed->hb (+accumb zero) | prep_we (FRAGMENT-ordered) | prep_wg.
// Weights prescaled by log2e.
__global__ __launch_bounds__(256) void k_misc(const int* __restrict__ x,
                                              const float* __restrict__ emb,
                                              const float* __restrict__ Wf1, const float* __restrict__ Ws1,
                                              const float* __restrict__ Wf2, const float* __restrict__ Ws2,
                                              const float* __restrict__ Wf3, const float* __restrict__ Ws3,
                                              unsigned short* __restrict__ hb,
                                              unsigned short* __restrict__ accumb,
                                              unsigned short* __restrict__ wedge,
                                              unsigned short* __restrict__ wgemm) {
  int b = blockIdx.x;
  int tid = threadIdx.x;
  if (b < 2000) {
    int idx = b * 256 + tid;   // 512000 = 32000*16
    int n = idx >> 4;
    int c8 = (idx & 15) << 3;
    const float* e = emb + (size_t)x[n] * 128 + c8;
    float4 v0 = *(const float4*)e;
    float4 v1 = *(const float4*)(e + 4);
    ushort4 p0, p1;
    p0.x = f2bf(v0.x); p0.y = f2bf(v0.y); p0.z = f2bf(v0.z); p0.w = f2bf(v0.w);
    p1.x = f2bf(v1.x); p1.y = f2bf(v1.y); p1.z = f2bf(v1.z); p1.w = f2bf(v1.w);
    unsigned short* hbp = hb + (size_t)n * 128 + c8;
    *(ushort4*)hbp = p0;
    *(ushort4*)(hbp + 4) = p1;
    *(uint4*)(accumb + (size_t)n * 128 + c8) = make_uint4(0, 0, 0, 0);
  } else if (b < 2096) {
    // wedge fragment-ordered (x log2e): r = ((w*4+t)*64 + lane)*8 + j
    // stores B(col = w*64 + t*16 + (lane&15), k = (lane>>4)*8 + j);
    // channel = w*32 + 2*(lane&15) + (t&1); t<2 -> Wf else Ws
    int idx = (b - 2000) * 256 + tid;    // 3*8192
    int l = idx >> 13;
    int r = idx & 8191;
    int j = r & 7;
    int lane = (r >> 3) & 63;
    int wt = r >> 9;                     // 0..15
    int w = wt >> 2, t = wt & 3;
    int c = lane & 15, q = lane >> 4;
    int k = q * 8 + j;
    const float* Wf = (l == 0) ? Wf1 : (l == 1) ? Wf2 : Wf3;
    const float* Ws = (l == 0) ? Ws1 : (l == 1) ? Ws2 : Ws3;
    const float* W = (t < 2) ? Wf : Ws;
    int ch = w * 32 + 2 * c + (t & 1);
    wedge[(size_t)l * 8192 + r] = f2bf(W[(size_t)(256 + k) * 128 + ch] * LOG2E);
  } else {
    // wgemm (x log2e): col cc -> T position p = (cc&~31) + 2*(cc&15) + ((cc>>4)&1).
    int idx = (b - 2096) * 256 + tid;    // 3*65536
    int l = idx >> 16;
    int r = idx & 65535;
    int cc = r >> 7;
    int k = r & 127;
    int p = (cc & ~31) + ((cc & 15) << 1) + ((cc >> 4) & 1);
    int ph = p & 255;
    int j = ph >> 2, sub = ph & 3;
    const float* Wf = (l == 0) ? Wf1 : (l == 1) ? Wf2 : Wf3;
    const float* Ws = (l == 0) ? Ws1 : (l == 1) ? Ws2 : Ws3;
    const float* W = (sub < 2) ? Wf : Ws;
    int ch = 2 * j + (sub & 1);
    int krow = ((p < 256) ? 0 : 128) + k;
    wgemm[(size_t)l * 65536 + cc * 128 + k] = f2bf(W[(size_t)krow * 128 + ch] * LOG2E);
  }
}

// Fused: hist (blocks 0..1249) | bstarts (blocks 1250..1375)
__global__ __launch_bounds__(256) void k_histb(const int* __restrict__ ei,
                                               const int* __restrict__ batch,
                                               int* __restrict__ counts,
                                               int* __restrict__ starts) {
  int b = blockIdx.x;
  int tid = threadIdx.x;
  if (b < 1250) {
    int e = b * 256 + tid;
    atomicAdd(counts + ei[NE + e], 1);
  } else {
    int n = (b - 1250) * 256 + tid;
    if (n > NN) return;
    if (n == NN) {
      starts[NG] = NN;
      int last = batch[NN - 1];
      for (int g = last + 1; g < NG; ++g) starts[g] = NN;
    } else if (n == 0) {
      int bb = batch[0];
      for (int g = 0; g <= bb; ++g) starts[g] = 0;
    } else {
      int b0 = batch[n - 1], b1 = batch[n];
      for (int g = b0 + 1; g <= b1; ++g) starts[g] = n;
    }
  }
}

// exclusive prefix sum of counts[32000] -> offs
__global__ __launch_bounds__(1024) void k_scan(const int* __restrict__ counts,
                                               int* __restrict__ offs) {
  __shared__ int part[1024];
  __shared__ int carry_s;
  int t = threadIdx.x;
  if (t == 0) carry_s = 0;
  __syncthreads();
  for (int chunk = 0; chunk < 4; ++chunk) {
    int base = chunk * 8192 + t * 8;
    int4 a = make_int4(0, 0, 0, 0), bq = make_int4(0, 0, 0, 0);
    bool full = (base + 8 <= NN);
    if (full) {
      a = *(const int4*)(counts + base);
      bq = *(const int4*)(counts + base + 4);
    }
    int e1 = a.x, e2 = e1 + a.y, e3 = e2 + a.z, e4 = e3 + a.w;
    int e5 = e4 + bq.x, e6 = e5 + bq.y, e7 = e6 + bq.z;
    int run = e7 + bq.w;
    part[t] = run;
    __syncthreads();
    for (int off = 1; off < 1024; off <<= 1) {
      int v = (t >= off) ? part[t - off] : 0;
      __syncthreads();
      part[t] += v;
      __syncthreads();
    }
    int excl = carry_s + ((t == 0) ? 0 : part[t - 1]);
    if (full) {
      int4 o0 = make_int4(excl, excl + e1, excl + e2, excl + e3);
      int4 o1 = make_int4(excl + e4, excl + e5, excl + e6, excl + e7);
      *(int4*)(offs + base) = o0;
      *(int4*)(offs + base + 4) = o1;
    }
    __syncthreads();
    if (t == 0) carry_s += part[1023];
    __syncthreads();
  }
}

// scatter pass 1: perm[pos] = original edge index
__global__ __launch_bounds__(256) void k_scat1(const int* __restrict__ ei,
                                               int* __restrict__ offs,
                                               int* __restrict__ perm) {
  int e = blockIdx.x * 256 + threadIdx.x;
  int d = ei[NE + e];
  int pos = atomicAdd(offs + d, 1);
  perm[pos] = e;
}

// Merged dispatch: blocks 0..1999 = layer-1 GEMM; blocks 2000..6999 = scatter pass 2.
__global__ __launch_bounds__(256) void k_s2g(const unsigned short* __restrict__ hb,
                                             const unsigned short* __restrict__ wgemmL,
                                             unsigned short* __restrict__ T,
                                             const int* __restrict__ ei,
                                             const float* __restrict__ ea,
                                             const int* __restrict__ perm,
                                             int* __restrict__ srcp,
                                             int* __restrict__ dstp,
                                             unsigned short* __restrict__ eab) {
  __shared__ short sA[64 * 136];
  __shared__ short sB[128 * 136];
  __shared__ int se[64];
  int b = blockIdx.x;
  int tid = threadIdx.x;
  if (b < 2000) {
    int m0 = (b >> 2) * 64;
    int n0 = (b & 3) * 128;
#pragma unroll
    for (int i = 0; i < 4; ++i) {
      int idx = tid + i * 256;
      int row = idx >> 4, chk = idx & 15;
      uint4 v = *(const uint4*)(hb + (size_t)(m0 + row) * 128 + chk * 8);
      *(uint4*)&sA[row * 136 + chk * 8] = v;
    }
#pragma unroll
    for (int i = 0; i < 8; ++i) {
      int idx = tid + i * 256;
      int col = idx >> 4, chk = idx & 15;
      uint4 v = *(const uint4*)(wgemmL + (size_t)(n0 + col) * 128 + chk * 8);
      *(uint4*)&sB[col * 136 + chk * 8] = v;
    }
    __syncthreads();
    int w = tid >> 6, lane = tid & 63, c = lane & 15, q = lane >> 4;
    frag_cd acc[4][2];
#pragma unroll
    for (int mt = 0; mt < 4; ++mt)
#pragma unroll
      for (int t = 0; t < 2; ++t) acc[mt][t] = (frag_cd){0.f, 0.f, 0.f, 0.f};
#pragma unroll
    for (int ks = 0; ks < 4; ++ks) {
      frag_ab Af[4], Bf[2];
#pragma unroll
      for (int mt = 0; mt < 4; ++mt)
        Af[mt] = *(const frag_ab*)&sA[(mt * 16 + c) * 136 + ks * 32 + q * 8];
#pragma unroll
      for (int t = 0; t < 2; ++t)
        Bf[t] = *(const frag_ab*)&sB[(w * 32 + t * 16 + c) * 136 + ks * 32 + q * 8];
#pragma unroll
      for (int mt = 0; mt < 4; ++mt)
#pragma unroll
        for (int t = 0; t < 2; ++t)
          acc[mt][t] = __builtin_amdgcn_mfma_f32_16x16x32_bf16(Af[mt], Bf[t], acc[mt][t], 0, 0, 0);
    }
    int nbase = n0 + w * 32 + 2 * c;
#pragma unroll
    for (int mt = 0; mt < 4; ++mt) {
#pragma unroll
      for (int r = 0; r < 4; ++r) {
        int node = m0 + mt * 16 + q * 4 + r;
        unsigned pk = (unsigned)f2bf(acc[mt][0][r]) | ((unsigned)f2bf(acc[mt][1][r]) << 16);
        *(unsigned*)(T + (size_t)node * 512 + nbase) = pk;
      }
    }
  } else {
    int base = (b - 2000) * 64;
    if (tid < 64) {
      int e = perm[base + tid];
      se[tid] = e;
      srcp[base + tid] = ei[e];
      dstp[base + tid] = ei[NE + e];
    }
    __syncthreads();
    int x = tid >> 2;
    int ck = tid & 3;
    int e = se[x];
    const float* a = ea + (size_t)e * 32 + ck * 8;
    float4 v0 = *(const float4*)a;
    float4 v1 = *(const float4*)(a + 4);
    int p = (((x >> 2) & 3) << 4) | ((x >> 4) << 2) | (x & 3);
    unsigned short* q = eab + (size_t)(base + p) * 32 + ck * 8;
    ushort4 o0, o1;
    o0.x = f2bf(v0.x); o0.y = f2bf(v0.y); o0.z = f2bf(v0.z); o0.w = f2bf(v0.w);
    o1.x = f2bf(v1.x); o1.y = f2bf(v1.y); o1.z = f2bf(v1.z); o1.w = f2bf(v1.w);
    *(ushort4*)q = o0;
    *(ushort4*)(q + 4) = o1;
  }
}

// Fused update + GEMM (layers 2,3): block owns 64 rows exclusively.
__global__ __launch_bounds__(256) void k_ugemm(unsigned short* __restrict__ hb,
                                               unsigned short* __restrict__ accumb,
                                               const unsigned short* __restrict__ wgemmL,
                                               unsigned short* __restrict__ T) {
  __shared__ short sA[64 * 136];
  __shared__ short sB[128 * 136];
  int m0 = blockIdx.x * 64;
  int tid = threadIdx.x;
#pragma unroll
  for (int i = 0; i < 4; ++i) {
    int idx = tid + i * 256;
    int row = idx >> 4, chk = idx & 15;
    size_t off = (size_t)(m0 + row) * 128 + chk * 8;
    uint4 a = *(uint4*)(accumb + off);
    uint4 hv = *(uint4*)(hb + off);
    float r0 = fmaxf(bflo(hv.x) + bflo(a.x), 0.f);
    float r1 = fmaxf(bfhi(hv.x) + bfhi(a.x), 0.f);
    float r2 = fmaxf(bflo(hv.y) + bflo(a.y), 0.f);
    float r3 = fmaxf(bfhi(hv.y) + bfhi(a.y), 0.f);
    float r4 = fmaxf(bflo(hv.z) + bflo(a.z), 0.f);
    float r5 = fmaxf(bfhi(hv.z) + bfhi(a.z), 0.f);
    float r6 = fmaxf(bflo(hv.w) + bflo(a.w), 0.f);
    float r7 = fmaxf(bfhi(hv.w) + bfhi(a.w), 0.f);
    uint4 o;
    o.x = (unsigned)f2bf(r0) | ((unsigned)f2bf(r1) << 16);
    o.y = (unsigned)f2bf(r2) | ((unsigned)f2bf(r3) << 16);
    o.z = (unsigned)f2bf(r4) | ((unsigned)f2bf(r5) << 16);
    o.w = (unsigned)f2bf(r6) | ((unsigned)f2bf(r7) << 16);
    *(uint4*)(hb + off) = o;
    *(uint4*)(accumb + off) = make_uint4(0, 0, 0, 0);
    *(uint4*)&sA[row * 136 + chk * 8] = o;
  }
  int w = tid >> 6, lane = tid & 63, c = lane & 15, q = lane >> 4;
#pragma unroll 1
  for (int nb = 0; nb < 4; ++nb) {
    int n0 = nb * 128;
    __syncthreads();
#pragma unroll
    for (int i = 0; i < 8; ++i) {
      int idx = tid + i * 256;
      int col = idx >> 4, chk = idx & 15;
      uint4 v = *(const uint4*)(wgemmL + (size_t)(n0 + col) * 128 + chk * 8);
      *(uint4*)&sB[col * 136 + chk * 8] = v;
    }
    __syncthreads();
    frag_cd acc[4][2];
#pragma unroll
    for (int mt = 0; mt < 4; ++mt)
#pragma unroll
      for (int t = 0; t < 2; ++t) acc[mt][t] = (frag_cd){0.f, 0.f, 0.f, 0.f};
#pragma unroll
    for (int ks = 0; ks < 4; ++ks) {
      frag_ab Af[4], Bf[2];
#pragma unroll
      for (int mt = 0; mt < 4; ++mt)
        Af[mt] = *(const frag_ab*)&sA[(mt * 16 + c) * 136 + ks * 32 + q * 8];
#pragma unroll
      for (int t = 0; t < 2; ++t)
        Bf[t] = *(const frag_ab*)&sB[(w * 32 + t * 16 + c) * 136 + ks * 32 + q * 8];
#pragma unroll
      for (int mt = 0; mt < 4; ++mt)
#pragma unroll
        for (int t = 0; t < 2; ++t)
          acc[mt][t] = __builtin_amdgcn_mfma_f32_16x16x32_bf16(Af[mt], Bf[t], acc[mt][t], 0, 0, 0);
    }
    int nbase = n0 + w * 32 + 2 * c;
#pragma unroll
    for (int mt = 0; mt < 4; ++mt) {
#pragma unroll
      for (int r = 0; r < 4; ++r) {
        int node = m0 + mt * 16 + q * 4 + r;
        unsigned pk = (unsigned)f2bf(acc[mt][0][r]) | ((unsigned)f2bf(acc[mt][1][r]) << 16);
        *(unsigned*)(T + (size_t)node * 512 + nbase) = pk;
      }
    }
  }
}

// Per-edge MFMA + dwordx2 gathers + register run-merge + packed bf16 atomics.
// 512 threads / 128 edges per block: wave = channel-group x edge-half.
// sB staged fragment-linear in LDS (16KB, trivial coalesced copy).
__global__ __launch_bounds__(512) void k_edge(const int* __restrict__ srcp,
                                              const int* __restrict__ dstp,
                                              const unsigned short* __restrict__ eab,
                                              const unsigned short* __restrict__ T,
                                              const unsigned short* __restrict__ wedgeL,
                                              const float* __restrict__ bf,
                                              const float* __restrict__ bs,
                                              unsigned short* __restrict__ accumb) {
  __shared__ short sA[128 * 40];
  __shared__ short sB[8192];
  __shared__ float sbf[128], sbs[128];
  __shared__ int sSrc[128], sDst[128];
  int tid = threadIdx.x;
  int e0 = blockIdx.x * 128;
  {
    int row = tid >> 2, qq = tid & 3;    // 512 threads cover 128 rows x 4 chunks
    uint4 v = *(const uint4*)(eab + (size_t)e0 * 32 + tid * 8);
    *(uint4*)&sA[row * 40 + qq * 8] = v;
  }
#pragma unroll
  for (int i = 0; i < 2; ++i) {          // 1024 uint4, fragment-linear
    int idx = tid + i * 512;
    uint4 v = *(const uint4*)(wedgeL + idx * 8);
    *(uint4*)&sB[idx * 8] = v;
  }
  if (tid < 128) {
    sbf[tid] = bf[tid] * LOG2E;
    sbs[tid] = bs[tid] * LOG2E;
  } else if (tid < 256) {
    sSrc[tid - 128] = srcp[e0 + tid - 128] * 512 + 256;
  } else if (tid < 384) {
    sDst[tid - 256] = dstp[e0 + tid - 256] * 512;
  }
  __syncthreads();

  int wave = tid >> 6;
  int w = wave & 3;          // channel group
  int eh = (wave >> 2) * 64; // edge-half base (0 or 64)
  int lane = tid & 63;
  int c = lane & 15;
  int q = lane >> 4;

  frag_ab Af[4], Bf[4];
#pragma unroll
  for (int et = 0; et < 4; ++et)
    Af[et] = *(const frag_ab*)&sA[(eh + et * 16 + c) * 40 + q * 8];
#pragma unroll
  for (int t = 0; t < 4; ++t)
    Bf[t] = *(const frag_ab*)&sB[((w * 4 + t) * 64 + lane) * 8];

  frag_cd acc[4][4];
#pragma unroll
  for (int et = 0; et < 4; ++et)
#pragma unroll
    for (int t = 0; t < 4; ++t)
      acc[et][t] = (frag_cd){0.f, 0.f, 0.f, 0.f};
#pragma unroll
  for (int et = 0; et < 4; ++et)
#pragma unroll
    for (int t = 0; t < 4; ++t)
      acc[et][t] = __builtin_amdgcn_mfma_f32_16x16x32_bf16(Af[et], Bf[t], acc[et][t], 0, 0, 0);

  int ch = w * 32 + 2 * c;
  int jo = ch * 2;
  v2f bfv = {sbf[ch], sbf[ch + 1]};
  v2f bsv = {sbs[ch], sbs[ch + 1]};

  int le0 = eh + q * 16;     // this lane's 16 consecutive sorted edges
  int prevd = sDst[le0];
  v2f av = {0.f, 0.f};
#pragma unroll
  for (int grp = 0; grp < 2; ++grp) {
    uint2 dv[8], sv[8];
#pragma unroll
    for (int i = 0; i < 8; ++i) {
      int e = le0 + grp * 8 + i;
      dv[i] = *(const uint2*)(T + sDst[e] + jo);
      sv[i] = *(const uint2*)(T + sSrc[e] + jo);
    }
    v2f m[8];
#pragma unroll
    for (int i = 0; i < 8; ++i) {
      int idx = grp * 8 + i;
      int et = idx >> 2, r = idx & 3;
      v2f xf = (v2f){acc[et][0][r], acc[et][1][r]} + unpk(dv[i].x) + unpk(sv[i].x) + bfv;
      v2f xs = (v2f){acc[et][2][r], acc[et][3][r]} + unpk(dv[i].y) + unpk(sv[i].y) + bsv;
      float g0 = __builtin_amdgcn_rcpf(1.f + __builtin_amdgcn_exp2f(-xf.x));
      float g1 = __builtin_amdgcn_rcpf(1.f + __builtin_amdgcn_exp2f(-xf.y));
      float sp0 = fmaxf(xs.x, 0.f) + __builtin_amdgcn_logf(1.f + __builtin_amdgcn_exp2f(-fabsf(xs.x)));
      float sp1 = fmaxf(xs.y, 0.f) + __builtin_amdgcn_logf(1.f + __builtin_amdgcn_exp2f(-fabsf(xs.y)));
      m[i] = (v2f){g0 * sp0, g1 * sp1};
    }
#pragma unroll
    for (int i = 0; i < 8; ++i) {
      int d = sDst[le0 + grp * 8 + i];
      if (d != prevd) {
        v2f o = av * LN2;
        unsigned pk = (unsigned)f2bf(o.x) | ((unsigned)f2bf(o.y) << 16);
        unsigned short* p = accumb + (size_t)(prevd >> 2) + ch;
        asm volatile("global_atomic_pk_add_bf16 %0, %1, off" :: "v"(p), "v"(pk) : "memory");
        av = (v2f){0.f, 0.f};
        prevd = d;
      }
      av += m[i];
    }
  }
  {
    v2f o = av * LN2;
    unsigned pk = (unsigned)f2bf(o.x) | ((unsigned)f2bf(o.y) << 16);
    unsigned short* p = accumb + (size_t)(prevd >> 2) + ch;
    asm volatile("global_atomic_pk_add_bf16 %0, %1, off" :: "v"(p), "v"(pk) : "memory");
  }
}

// Fused layer-3 update + segmented mean-pool + final matmul
__global__ __launch_bounds__(128) void k_pool_final(const unsigned short* __restrict__ hb,
                                                    const unsigned short* __restrict__ accumb,
                                                    const int* __restrict__ starts,
                                                    const float* __restrict__ Wlin,
                                                    const float* __restrict__ blin,
                                                    float* __restrict__ out) {
  __shared__ float p[128];
  int g = blockIdx.x, c = threadIdx.x;
  int s0 = starts[g], s1 = starts[g + 1];
  float acc = 0.f;
  for (int n = s0; n < s1; ++n) {
    float hv = bfs(hb[(size_t)n * 128 + c]);
    float av = bfs(accumb[(size_t)n * 128 + c]);
    acc += fmaxf(hv + av, 0.f);
  }
  float inv = 1.f / fmaxf((float)(s1 - s0), 1.f);
  p[c] = acc * inv;
  __syncthreads();
  float o = blin[c];
#pragma unroll 8
  for (int k = 0; k < 128; ++k) o += p[k] * Wlin[k * 128 + c];
  out[(size_t)g * 128 + c] = o;
}

extern "C" void kernel_launch(void* const* d_in, const int* in_sizes, int n_in,
                              void* d_out, int out_size, void* d_ws, size_t ws_size,
                              hipStream_t stream) {
  const int* x = (const int*)d_in[0];
  const int* ei = (const int*)d_in[1];
  const float* ea = (const float*)d_in[2];
  const int* batch = (const int*)d_in[3];
  const float* emb = (const float*)d_in[4];
  const float* Wf[3] = {(const float*)d_in[5], (const float*)d_in[9], (const float*)d_in[13]};
  const float* bf[3] = {(const float*)d_in[6], (const float*)d_in[10], (const float*)d_in[14]};
  const float* Wsm[3] = {(const float*)d_in[7], (const float*)d_in[11], (const float*)d_in[15]};
  const float* bs[3] = {(const float*)d_in[8], (const float*)d_in[12], (const float*)d_in[16]};
  const float* Wlin = (const float*)d_in[17];
  const float* blin = (const float*)d_in[18];
  float* out = (float*)d_out;

  char* ws = (char*)d_ws;
  unsigned short* hb = (unsigned short*)ws;     ws += (size_t)NN * 128 * 2;
  unsigned short* accumb = (unsigned short*)ws; ws += (size_t)NN * 128 * 2;
  unsigned short* T = (unsigned short*)ws;      ws += (size_t)NN * 512 * 2;
  unsigned short* eab = (unsigned short*)ws;    ws += (size_t)NE * 32 * 2;
  unsigned short* wedge = (unsigned short*)ws;  ws += 3 * 8192 * 2;
  unsigned short* wgemm = (unsigned short*)ws;  ws += 3 * 65536 * 2;
  int* counts = (int*)ws;                       ws += (size_t)NN * 4;   // zeroed
  int* offs = (int*)ws;                         ws += (size_t)NN * 4;
  int* srcp = (int*)ws;                         ws += (size_t)NE * 4;
  int* dstp = (int*)ws;                         ws += (size_t)NE * 4;
  int* perm = (int*)ws;                         ws += (size_t)NE * 4;
  int* starts = (int*)ws;                       ws += (size_t)(NG + 1) * 4;

  hipMemsetAsync(counts, 0, (size_t)NN * 4, stream);
  k_misc<<<2864, 256, 0, stream>>>(x, emb, Wf[0], Wsm[0], Wf[1], Wsm[1], Wf[2], Wsm[2],
                                   hb, accumb, wedge, wgemm);
  k_histb<<<1376, 256, 0, stream>>>(ei, batch, counts, starts);
  k_scan<<<1, 1024, 0, stream>>>(counts, offs);
  k_scat1<<<1250, 256, 0, stream>>>(ei, offs, perm);
  k_s2g<<<7000, 256, 0, stream>>>(hb, wgemm, T, ei, ea, perm, srcp, dstp, eab);
  for (int l = 0; l < 3; ++l) {
    if (l > 0)
      k_ugemm<<<500, 256, 0, stream>>>(hb, accumb, wgemm + (size_t)l * 65536, T);
    k_edge<<<2500, 512, 0, stream>>>(srcp, dstp, eab, T, wedge + (size_t)l * 8192,
                                     bf[l], bs[l], accumb);
  }
  k_pool_final<<<1600, 128, 0, stream>>>(hb, accumb, starts, Wlin, blin, out);
}

// Round 15
// 346.255 us; speedup vs baseline: 1.0557x; 1.0142x over previous
//
#include <hip/hip_runtime.h>
#include <math.h>

#define NN 32000
#define NE 320000
#define NG 1600
#define LOG2E 1.4426950408889634f
#define LN2   0.6931471805599453f

using frag_ab = __attribute__((ext_vector_type(8))) short;   // 8 bf16 (4 VGPRs)
using frag_cd = __attribute__((ext_vector_type(4))) float;   // 4 fp32
typedef float v2f __attribute__((ext_vector_type(2)));

static __device__ __forceinline__ unsigned short f2bf(float f) {
  unsigned u = __builtin_bit_cast(unsigned, f);
  unsigned r = u + 0x7fff + ((u >> 16) & 1);   // RNE
  return (unsigned short)(r >> 16);
}
static __device__ __forceinline__ float bflo(unsigned u) {
  return __builtin_bit_cast(float, u << 16);
}
static __device__ __forceinline__ float bfhi(unsigned u) {
  return __builtin_bit_cast(float, u & 0xffff0000u);
}
static __device__ __forceinline__ float bfs(unsigned short u) {
  return __builtin_bit_cast(float, (unsigned)u << 16);
}
static __device__ __forceinline__ v2f unpk(unsigned u) {
  return (v2f){bflo(u), bfhi(u)};
}

// Fused: embed->hb (+accumb zero) | prep_we (FRAGMENT-ordered) | prep_wg.
// Weights prescaled by log2e.
__global__ __launch_bounds__(256) void k_misc(const int* __restrict__ x,
                                              const float* __restrict__ emb,
                                              const float* __restrict__ Wf1, const float* __restrict__ Ws1,
                                              const float* __restrict__ Wf2, const float* __restrict__ Ws2,
                                              const float* __restrict__ Wf3, const float* __restrict__ Ws3,
                                              unsigned short* __restrict__ hb,
                                              unsigned short* __restrict__ accumb,
                                              unsigned short* __restrict__ wedge,
                                              unsigned short* __restrict__ wgemm) {
  int b = blockIdx.x;
  int tid = threadIdx.x;
  if (b < 2000) {
    int idx = b * 256 + tid;   // 512000 = 32000*16
    int n = idx >> 4;
    int c8 = (idx & 15) << 3;
    const float* e = emb + (size_t)x[n] * 128 + c8;
    float4 v0 = *(const float4*)e;
    float4 v1 = *(const float4*)(e + 4);
    ushort4 p0, p1;
    p0.x = f2bf(v0.x); p0.y = f2bf(v0.y); p0.z = f2bf(v0.z); p0.w = f2bf(v0.w);
    p1.x = f2bf(v1.x); p1.y = f2bf(v1.y); p1.z = f2bf(v1.z); p1.w = f2bf(v1.w);
    unsigned short* hbp = hb + (size_t)n * 128 + c8;
    *(ushort4*)hbp = p0;
    *(ushort4*)(hbp + 4) = p1;
    *(uint4*)(accumb + (size_t)n * 128 + c8) = make_uint4(0, 0, 0, 0);
  } else if (b < 2096) {
    // wedge fragment-ordered (x log2e): r = ((w*4+t)*64 + lane)*8 + j
    // stores B(col = w*64 + t*16 + (lane&15), k = (lane>>4)*8 + j);
    // channel = w*32 + 2*(lane&15) + (t&1); t<2 -> Wf else Ws
    int idx = (b - 2000) * 256 + tid;    // 3*8192
    int l = idx >> 13;
    int r = idx & 8191;
    int j = r & 7;
    int lane = (r >> 3) & 63;
    int wt = r >> 9;                     // 0..15
    int w = wt >> 2, t = wt & 3;
    int c = lane & 15, q = lane >> 4;
    int k = q * 8 + j;
    const float* Wf = (l == 0) ? Wf1 : (l == 1) ? Wf2 : Wf3;
    const float* Ws = (l == 0) ? Ws1 : (l == 1) ? Ws2 : Ws3;
    const float* W = (t < 2) ? Wf : Ws;
    int ch = w * 32 + 2 * c + (t & 1);
    wedge[(size_t)l * 8192 + r] = f2bf(W[(size_t)(256 + k) * 128 + ch] * LOG2E);
  } else {
    // wgemm (x log2e): col cc -> T position p = (cc&~31) + 2*(cc&15) + ((cc>>4)&1).
    int idx = (b - 2096) * 256 + tid;    // 3*65536
    int l = idx >> 16;
    int r = idx & 65535;
    int cc = r >> 7;
    int k = r & 127;
    int p = (cc & ~31) + ((cc & 15) << 1) + ((cc >> 4) & 1);
    int ph = p & 255;
    int j = ph >> 2, sub = ph & 3;
    const float* Wf = (l == 0) ? Wf1 : (l == 1) ? Wf2 : Wf3;
    const float* Ws = (l == 0) ? Ws1 : (l == 1) ? Ws2 : Ws3;
    const float* W = (sub < 2) ? Wf : Ws;
    int ch = 2 * j + (sub & 1);
    int krow = ((p < 256) ? 0 : 128) + k;
    wgemm[(size_t)l * 65536 + cc * 128 + k] = f2bf(W[(size_t)krow * 128 + ch] * LOG2E);
  }
}

// Fused: hist (blocks 0..1249) | bstarts (blocks 1250..1375)
__global__ __launch_bounds__(256) void k_histb(const int* __restrict__ ei,
                                               const int* __restrict__ batch,
                                               int* __restrict__ counts,
                                               int* __restrict__ starts) {
  int b = blockIdx.x;
  int tid = threadIdx.x;
  if (b < 1250) {
    int e = b * 256 + tid;
    atomicAdd(counts + ei[NE + e], 1);
  } else {
    int n = (b - 1250) * 256 + tid;
    if (n > NN) return;
    if (n == NN) {
      starts[NG] = NN;
      int last = batch[NN - 1];
      for (int g = last + 1; g < NG; ++g) starts[g] = NN;
    } else if (n == 0) {
      int bb = batch[0];
      for (int g = 0; g <= bb; ++g) starts[g] = 0;
    } else {
      int b0 = batch[n - 1], b1 = batch[n];
      for (int g = b0 + 1; g <= b1; ++g) starts[g] = n;
    }
  }
}

// exclusive prefix sum of counts[32000] -> offs
__global__ __launch_bounds__(1024) void k_scan(const int* __restrict__ counts,
                                               int* __restrict__ offs) {
  __shared__ int part[1024];
  __shared__ int carry_s;
  int t = threadIdx.x;
  if (t == 0) carry_s = 0;
  __syncthreads();
  for (int chunk = 0; chunk < 4; ++chunk) {
    int base = chunk * 8192 + t * 8;
    int4 a = make_int4(0, 0, 0, 0), bq = make_int4(0, 0, 0, 0);
    bool full = (base + 8 <= NN);
    if (full) {
      a = *(const int4*)(counts + base);
      bq = *(const int4*)(counts + base + 4);
    }
    int e1 = a.x, e2 = e1 + a.y, e3 = e2 + a.z, e4 = e3 + a.w;
    int e5 = e4 + bq.x, e6 = e5 + bq.y, e7 = e6 + bq.z;
    int run = e7 + bq.w;
    part[t] = run;
    __syncthreads();
    for (int off = 1; off < 1024; off <<= 1) {
      int v = (t >= off) ? part[t - off] : 0;
      __syncthreads();
      part[t] += v;
      __syncthreads();
    }
    int excl = carry_s + ((t == 0) ? 0 : part[t - 1]);
    if (full) {
      int4 o0 = make_int4(excl, excl + e1, excl + e2, excl + e3);
      int4 o1 = make_int4(excl + e4, excl + e5, excl + e6, excl + e7);
      *(int4*)(offs + base) = o0;
      *(int4*)(offs + base + 4) = o1;
    }
    __syncthreads();
    if (t == 0) carry_s += part[1023];
    __syncthreads();
  }
}

// scatter pass 1: perm[pos] = original edge index
__global__ __launch_bounds__(256) void k_scat1(const int* __restrict__ ei,
                                               int* __restrict__ offs,
                                               int* __restrict__ perm) {
  int e = blockIdx.x * 256 + threadIdx.x;
  int d = ei[NE + e];
  int pos = atomicAdd(offs + d, 1);
  perm[pos] = e;
}

// Merged dispatch: blocks 0..1999 = layer-1 GEMM; blocks 2000..6999 = scatter pass 2.
__global__ __launch_bounds__(256) void k_s2g(const unsigned short* __restrict__ hb,
                                             const unsigned short* __restrict__ wgemmL,
                                             unsigned short* __restrict__ T,
                                             const int* __restrict__ ei,
                                             const float* __restrict__ ea,
                                             const int* __restrict__ perm,
                                             int* __restrict__ srcp,
                                             int* __restrict__ dstp,
                                             unsigned short* __restrict__ eab) {
  __shared__ short sA[64 * 136];
  __shared__ short sB[128 * 136];
  __shared__ int se[64];
  int b = blockIdx.x;
  int tid = threadIdx.x;
  if (b < 2000) {
    int m0 = (b >> 2) * 64;
    int n0 = (b & 3) * 128;
#pragma unroll
    for (int i = 0; i < 4; ++i) {
      int idx = tid + i * 256;
      int row = idx >> 4, chk = idx & 15;
      uint4 v = *(const uint4*)(hb + (size_t)(m0 + row) * 128 + chk * 8);
      *(uint4*)&sA[row * 136 + chk * 8] = v;
    }
#pragma unroll
    for (int i = 0; i < 8; ++i) {
      int idx = tid + i * 256;
      int col = idx >> 4, chk = idx & 15;
      uint4 v = *(const uint4*)(wgemmL + (size_t)(n0 + col) * 128 + chk * 8);
      *(uint4*)&sB[col * 136 + chk * 8] = v;
    }
    __syncthreads();
    int w = tid >> 6, lane = tid & 63, c = lane & 15, q = lane >> 4;
    frag_cd acc[4][2];
#pragma unroll
    for (int mt = 0; mt < 4; ++mt)
#pragma unroll
      for (int t = 0; t < 2; ++t) acc[mt][t] = (frag_cd){0.f, 0.f, 0.f, 0.f};
#pragma unroll
    for (int ks = 0; ks < 4; ++ks) {
      frag_ab Af[4], Bf[2];
#pragma unroll
      for (int mt = 0; mt < 4; ++mt)
        Af[mt] = *(const frag_ab*)&sA[(mt * 16 + c) * 136 + ks * 32 + q * 8];
#pragma unroll
      for (int t = 0; t < 2; ++t)
        Bf[t] = *(const frag_ab*)&sB[(w * 32 + t * 16 + c) * 136 + ks * 32 + q * 8];
#pragma unroll
      for (int mt = 0; mt < 4; ++mt)
#pragma unroll
        for (int t = 0; t < 2; ++t)
          acc[mt][t] = __builtin_amdgcn_mfma_f32_16x16x32_bf16(Af[mt], Bf[t], acc[mt][t], 0, 0, 0);
    }
    int nbase = n0 + w * 32 + 2 * c;
#pragma unroll
    for (int mt = 0; mt < 4; ++mt) {
#pragma unroll
      for (int r = 0; r < 4; ++r) {
        int node = m0 + mt * 16 + q * 4 + r;
        unsigned pk = (unsigned)f2bf(acc[mt][0][r]) | ((unsigned)f2bf(acc[mt][1][r]) << 16);
        *(unsigned*)(T + (size_t)node * 512 + nbase) = pk;
      }
    }
  } else {
    int base = (b - 2000) * 64;
    if (tid < 64) {
      int e = perm[base + tid];
      se[tid] = e;
      srcp[base + tid] = ei[e];
      dstp[base + tid] = ei[NE + e];
    }
    __syncthreads();
    int x = tid >> 2;
    int ck = tid & 3;
    int e = se[x];
    const float* a = ea + (size_t)e * 32 + ck * 8;
    float4 v0 = *(const float4*)a;
    float4 v1 = *(const float4*)(a + 4);
    int p = (((x >> 2) & 3) << 4) | ((x >> 4) << 2) | (x & 3);
    unsigned short* q = eab + (size_t)(base + p) * 32 + ck * 8;
    ushort4 o0, o1;
    o0.x = f2bf(v0.x); o0.y = f2bf(v0.y); o0.z = f2bf(v0.z); o0.w = f2bf(v0.w);
    o1.x = f2bf(v1.x); o1.y = f2bf(v1.y); o1.z = f2bf(v1.z); o1.w = f2bf(v1.w);
    *(ushort4*)q = o0;
    *(ushort4*)(q + 4) = o1;
  }
}

// Fused update + GEMM (layers 2,3): block owns 64 rows exclusively.
__global__ __launch_bounds__(256) void k_ugemm(unsigned short* __restrict__ hb,
                                               unsigned short* __restrict__ accumb,
                                               const unsigned short* __restrict__ wgemmL,
                                               unsigned short* __restrict__ T) {
  __shared__ short sA[64 * 136];
  __shared__ short sB[128 * 136];
  int m0 = blockIdx.x * 64;
  int tid = threadIdx.x;
#pragma unroll
  for (int i = 0; i < 4; ++i) {
    int idx = tid + i * 256;
    int row = idx >> 4, chk = idx & 15;
    size_t off = (size_t)(m0 + row) * 128 + chk * 8;
    uint4 a = *(uint4*)(accumb + off);
    uint4 hv = *(uint4*)(hb + off);
    float r0 = fmaxf(bflo(hv.x) + bflo(a.x), 0.f);
    float r1 = fmaxf(bfhi(hv.x) + bfhi(a.x), 0.f);
    float r2 = fmaxf(bflo(hv.y) + bflo(a.y), 0.f);
    float r3 = fmaxf(bfhi(hv.y) + bfhi(a.y), 0.f);
    float r4 = fmaxf(bflo(hv.z) + bflo(a.z), 0.f);
    float r5 = fmaxf(bfhi(hv.z) + bfhi(a.z), 0.f);
    float r6 = fmaxf(bflo(hv.w) + bflo(a.w), 0.f);
    float r7 = fmaxf(bfhi(hv.w) + bfhi(a.w), 0.f);
    uint4 o;
    o.x = (unsigned)f2bf(r0) | ((unsigned)f2bf(r1) << 16);
    o.y = (unsigned)f2bf(r2) | ((unsigned)f2bf(r3) << 16);
    o.z = (unsigned)f2bf(r4) | ((unsigned)f2bf(r5) << 16);
    o.w = (unsigned)f2bf(r6) | ((unsigned)f2bf(r7) << 16);
    *(uint4*)(hb + off) = o;
    *(uint4*)(accumb + off) = make_uint4(0, 0, 0, 0);
    *(uint4*)&sA[row * 136 + chk * 8] = o;
  }
  int w = tid >> 6, lane = tid & 63, c = lane & 15, q = lane >> 4;
#pragma unroll 1
  for (int nb = 0; nb < 4; ++nb) {
    int n0 = nb * 128;
    __syncthreads();
#pragma unroll
    for (int i = 0; i < 8; ++i) {
      int idx = tid + i * 256;
      int col = idx >> 4, chk = idx & 15;
      uint4 v = *(const uint4*)(wgemmL + (size_t)(n0 + col) * 128 + chk * 8);
      *(uint4*)&sB[col * 136 + chk * 8] = v;
    }
    __syncthreads();
    frag_cd acc[4][2];
#pragma unroll
    for (int mt = 0; mt < 4; ++mt)
#pragma unroll
      for (int t = 0; t < 2; ++t) acc[mt][t] = (frag_cd){0.f, 0.f, 0.f, 0.f};
#pragma unroll
    for (int ks = 0; ks < 4; ++ks) {
      frag_ab Af[4], Bf[2];
#pragma unroll
      for (int mt = 0; mt < 4; ++mt)
        Af[mt] = *(const frag_ab*)&sA[(mt * 16 + c) * 136 + ks * 32 + q * 8];
#pragma unroll
      for (int t = 0; t < 2; ++t)
        Bf[t] = *(const frag_ab*)&sB[(w * 32 + t * 16 + c) * 136 + ks * 32 + q * 8];
#pragma unroll
      for (int mt = 0; mt < 4; ++mt)
#pragma unroll
        for (int t = 0; t < 2; ++t)
          acc[mt][t] = __builtin_amdgcn_mfma_f32_16x16x32_bf16(Af[mt], Bf[t], acc[mt][t], 0, 0, 0);
    }
    int nbase = n0 + w * 32 + 2 * c;
#pragma unroll
    for (int mt = 0; mt < 4; ++mt) {
#pragma unroll
      for (int r = 0; r < 4; ++r) {
        int node = m0 + mt * 16 + q * 4 + r;
        unsigned pk = (unsigned)f2bf(acc[mt][0][r]) | ((unsigned)f2bf(acc[mt][1][r]) << 16);
        *(unsigned*)(T + (size_t)node * 512 + nbase) = pk;
      }
    }
  }
}

// Per-edge MFMA + software-pipelined gather/epilogue + register run-merge +
// packed bf16 atomics. 512 threads / 128 edges per block.
// Bias (x log2e) folded into the MFMA accumulator init (C-operand).
__global__ __launch_bounds__(512) void k_edge(const int* __restrict__ srcp,
                                              const int* __restrict__ dstp,
                                              const unsigned short* __restrict__ eab,
                                              const unsigned short* __restrict__ T,
                                              const unsigned short* __restrict__ wedgeL,
                                              const float* __restrict__ bf,
                                              const float* __restrict__ bs,
                                              unsigned short* __restrict__ accumb) {
  __shared__ short sA[128 * 40];
  __shared__ short sB[8192];
  __shared__ float sbf[128], sbs[128];
  __shared__ int sSrc[128], sDst[128];
  int tid = threadIdx.x;
  int e0 = blockIdx.x * 128;
  {
    int row = tid >> 2, qq = tid & 3;    // 512 threads cover 128 rows x 4 chunks
    uint4 v = *(const uint4*)(eab + (size_t)e0 * 32 + tid * 8);
    *(uint4*)&sA[row * 40 + qq * 8] = v;
  }
#pragma unroll
  for (int i = 0; i < 2; ++i) {          // 1024 uint4, fragment-linear
    int idx = tid + i * 512;
    uint4 v = *(const uint4*)(wedgeL + idx * 8);
    *(uint4*)&sB[idx * 8] = v;
  }
  if (tid < 128) {
    sbf[tid] = bf[tid] * LOG2E;
    sbs[tid] = bs[tid] * LOG2E;
  } else if (tid < 256) {
    sSrc[tid - 128] = srcp[e0 + tid - 128] * 512 + 256;
  } else if (tid < 384) {
    sDst[tid - 256] = dstp[e0 + tid - 256] * 512;
  }
  __syncthreads();

  int wave = tid >> 6;
  int w = wave & 3;          // channel group
  int eh = (wave >> 2) * 64; // edge-half base (0 or 64)
  int lane = tid & 63;
  int c = lane & 15;
  int q = lane >> 4;

  int ch = w * 32 + 2 * c;
  int jo = ch * 2;
  v2f bfv = {sbf[ch], sbf[ch + 1]};
  v2f bsv = {sbs[ch], sbs[ch + 1]};

  frag_ab Af[4], Bf[4];
#pragma unroll
  for (int et = 0; et < 4; ++et)
    Af[et] = *(const frag_ab*)&sA[(eh + et * 16 + c) * 40 + q * 8];
#pragma unroll
  for (int t = 0; t < 4; ++t)
    Bf[t] = *(const frag_ab*)&sB[((w * 4 + t) * 64 + lane) * 8];

  // bias folded into C-operand: acc[et][0/1] = bf[ch]/bf[ch+1]; [2/3] = bs
  frag_cd acc[4][4];
#pragma unroll
  for (int et = 0; et < 4; ++et) {
    acc[et][0] = (frag_cd){bfv.x, bfv.x, bfv.x, bfv.x};
    acc[et][1] = (frag_cd){bfv.y, bfv.y, bfv.y, bfv.y};
    acc[et][2] = (frag_cd){bsv.x, bsv.x, bsv.x, bsv.x};
    acc[et][3] = (frag_cd){bsv.y, bsv.y, bsv.y, bsv.y};
  }
#pragma unroll
  for (int et = 0; et < 4; ++et)
#pragma unroll
    for (int t = 0; t < 4; ++t)
      acc[et][t] = __builtin_amdgcn_mfma_f32_16x16x32_bf16(Af[et], Bf[t], acc[et][t], 0, 0, 0);

  int le0 = eh + q * 16;     // this lane's 16 consecutive sorted edges
  int prevd = sDst[le0];
  v2f av = {0.f, 0.f};

  // software-pipelined: 4 groups of 4 edges, one-group-deep prefetch.
  // group g's accumulator slice is acc[g][*][i] (et = g, r = i).
  uint2 dvb[2][4], svb[2][4];
#pragma unroll
  for (int i = 0; i < 4; ++i) {
    int e = le0 + i;
    dvb[0][i] = *(const uint2*)(T + sDst[e] + jo);
    svb[0][i] = *(const uint2*)(T + sSrc[e] + jo);
  }
#pragma unroll
  for (int g = 0; g < 4; ++g) {
    int cur = g & 1, nxt = cur ^ 1;
    if (g < 3) {
#pragma unroll
      for (int i = 0; i < 4; ++i) {
        int e = le0 + (g + 1) * 4 + i;
        dvb[nxt][i] = *(const uint2*)(T + sDst[e] + jo);
        svb[nxt][i] = *(const uint2*)(T + sSrc[e] + jo);
      }
    }
    v2f m[4];
#pragma unroll
    for (int i = 0; i < 4; ++i) {
      v2f xf = (v2f){acc[g][0][i], acc[g][1][i]} + unpk(dvb[cur][i].x) + unpk(svb[cur][i].x);
      v2f xs = (v2f){acc[g][2][i], acc[g][3][i]} + unpk(dvb[cur][i].y) + unpk(svb[cur][i].y);
      float g0 = __builtin_amdgcn_rcpf(1.f + __builtin_amdgcn_exp2f(-xf.x));
      float g1 = __builtin_amdgcn_rcpf(1.f + __builtin_amdgcn_exp2f(-xf.y));
      float sp0 = fmaxf(xs.x, 0.f) + __builtin_amdgcn_logf(1.f + __builtin_amdgcn_exp2f(-fabsf(xs.x)));
      float sp1 = fmaxf(xs.y, 0.f) + __builtin_amdgcn_logf(1.f + __builtin_amdgcn_exp2f(-fabsf(xs.y)));
      m[i] = (v2f){g0 * sp0, g1 * sp1};
    }
#pragma unroll
    for (int i = 0; i < 4; ++i) {
      int d = sDst[le0 + g * 4 + i];
      if (d != prevd) {
        v2f o = av * LN2;
        unsigned pk = (unsigned)f2bf(o.x) | ((unsigned)f2bf(o.y) << 16);
        unsigned short* p = accumb + (size_t)(prevd >> 2) + ch;
        asm volatile("global_atomic_pk_add_bf16 %0, %1, off" :: "v"(p), "v"(pk) : "memory");
        av = (v2f){0.f, 0.f};
        prevd = d;
      }
      av += m[i];
    }
  }
  {
    v2f o = av * LN2;
    unsigned pk = (unsigned)f2bf(o.x) | ((unsigned)f2bf(o.y) << 16);
    unsigned short* p = accumb + (size_t)(prevd >> 2) + ch;
    asm volatile("global_atomic_pk_add_bf16 %0, %1, off" :: "v"(p), "v"(pk) : "memory");
  }
}

// Fused layer-3 update + segmented mean-pool + final matmul
__global__ __launch_bounds__(128) void k_pool_final(const unsigned short* __restrict__ hb,
                                                    const unsigned short* __restrict__ accumb,
                                                    const int* __restrict__ starts,
                                                    const float* __restrict__ Wlin,
                                                    const float* __restrict__ blin,
                                                    float* __restrict__ out) {
  __shared__ float p[128];
  int g = blockIdx.x, c = threadIdx.x;
  int s0 = starts[g], s1 = starts[g + 1];
  float acc = 0.f;
  for (int n = s0; n < s1; ++n) {
    float hv = bfs(hb[(size_t)n * 128 + c]);
    float av = bfs(accumb[(size_t)n * 128 + c]);
    acc += fmaxf(hv + av, 0.f);
  }
  float inv = 1.f / fmaxf((float)(s1 - s0), 1.f);
  p[c] = acc * inv;
  __syncthreads();
  float o = blin[c];
#pragma unroll 8
  for (int k = 0; k < 128; ++k) o += p[k] * Wlin[k * 128 + c];
  out[(size_t)g * 128 + c] = o;
}

extern "C" void kernel_launch(void* const* d_in, const int* in_sizes, int n_in,
                              void* d_out, int out_size, void* d_ws, size_t ws_size,
                              hipStream_t stream) {
  const int* x = (const int*)d_in[0];
  const int* ei = (const int*)d_in[1];
  const float* ea = (const float*)d_in[2];
  const int* batch = (const int*)d_in[3];
  const float* emb = (const float*)d_in[4];
  const float* Wf[3] = {(const float*)d_in[5], (const float*)d_in[9], (const float*)d_in[13]};
  const float* bf[3] = {(const float*)d_in[6], (const float*)d_in[10], (const float*)d_in[14]};
  const float* Wsm[3] = {(const float*)d_in[7], (const float*)d_in[11], (const float*)d_in[15]};
  const float* bs[3] = {(const float*)d_in[8], (const float*)d_in[12], (const float*)d_in[16]};
  const float* Wlin = (const float*)d_in[17];
  const float* blin = (const float*)d_in[18];
  float* out = (float*)d_out;

  char* ws = (char*)d_ws;
  unsigned short* hb = (unsigned short*)ws;     ws += (size_t)NN * 128 * 2;
  unsigned short* accumb = (unsigned short*)ws; ws += (size_t)NN * 128 * 2;
  unsigned short* T = (unsigned short*)ws;      ws += (size_t)NN * 512 * 2;
  unsigned short* eab = (unsigned short*)ws;    ws += (size_t)NE * 32 * 2;
  unsigned short* wedge = (unsigned short*)ws;  ws += 3 * 8192 * 2;
  unsigned short* wgemm = (unsigned short*)ws;  ws += 3 * 65536 * 2;
  int* counts = (int*)ws;                       ws += (size_t)NN * 4;   // zeroed
  int* offs = (int*)ws;                         ws += (size_t)NN * 4;
  int* srcp = (int*)ws;                         ws += (size_t)NE * 4;
  int* dstp = (int*)ws;                         ws += (size_t)NE * 4;
  int* perm = (int*)ws;                         ws += (size_t)NE * 4;
  int* starts = (int*)ws;                       ws += (size_t)(NG + 1) * 4;

  hipMemsetAsync(counts, 0, (size_t)NN * 4, stream);
  k_misc<<<2864, 256, 0, stream>>>(x, emb, Wf[0], Wsm[0], Wf[1], Wsm[1], Wf[2], Wsm[2],
                                   hb, accumb, wedge, wgemm);
  k_histb<<<1376, 256, 0, stream>>>(ei, batch, counts, starts);
  k_scan<<<1, 1024, 0, stream>>>(counts, offs);
  k_scat1<<<1250, 256, 0, stream>>>(ei, offs, perm);
  k_s2g<<<7000, 256, 0, stream>>>(hb, wgemm, T, ei, ea, perm, srcp, dstp, eab);
  for (int l = 0; l < 3; ++l) {
    if (l > 0)
      k_ugemm<<<500, 256, 0, stream>>>(hb, accumb, wgemm + (size_t)l * 65536, T);
    k_edge<<<2500, 512, 0, stream>>>(srcp, dstp, eab, T, wedge + (size_t)l * 8192,
                                     bf[l], bs[l], accumb);
  }
  k_pool_final<<<1600, 128, 0, stream>>>(hb, accumb, starts, Wlin, blin, out);
}

// Round 16
// 344.032 us; speedup vs baseline: 1.0625x; 1.0065x over previous
//
#include <hip/hip_runtime.h>
#include <math.h>

#define NN 32000
#define NE 320000
#define NG 1600
#define LOG2E 1.4426950408889634f
#define LN2   0.6931471805599453f

using frag_ab = __attribute__((ext_vector_type(8))) short;   // 8 bf16 (4 VGPRs)
using frag_cd = __attribute__((ext_vector_type(4))) float;   // 4 fp32
typedef float v2f __attribute__((ext_vector_type(2)));

static __device__ __forceinline__ unsigned short f2bf(float f) {
  unsigned u = __builtin_bit_cast(unsigned, f);
  unsigned r = u + 0x7fff + ((u >> 16) & 1);   // RNE
  return (unsigned short)(r >> 16);
}
static __device__ __forceinline__ float bflo(unsigned u) {
  return __builtin_bit_cast(float, u << 16);
}
static __device__ __forceinline__ float bfhi(unsigned u) {
  return __builtin_bit_cast(float, u & 0xffff0000u);
}
static __device__ __forceinline__ float bfs(unsigned short u) {
  return __builtin_bit_cast(float, (unsigned)u << 16);
}
static __device__ __forceinline__ v2f unpk(unsigned u) {
  return (v2f){bflo(u), bfhi(u)};
}

// Phase-0 fused: prep_we (fragment-ordered) | prep_wg | hist | bstarts.
// Weights prescaled by log2e.
__global__ __launch_bounds__(256) void k_prephist(const float* __restrict__ Wf1, const float* __restrict__ Ws1,
                                                  const float* __restrict__ Wf2, const float* __restrict__ Ws2,
                                                  const float* __restrict__ Wf3, const float* __restrict__ Ws3,
                                                  const int* __restrict__ ei,
                                                  const int* __restrict__ batch,
                                                  unsigned short* __restrict__ wedge,
                                                  unsigned short* __restrict__ wgemm,
                                                  int* __restrict__ counts,
                                                  int* __restrict__ starts) {
  int b = blockIdx.x;
  int tid = threadIdx.x;
  if (b < 96) {
    // wedge fragment-ordered (x log2e): r = ((w*4+t)*64 + lane)*8 + j
    int idx = b * 256 + tid;             // 3*8192
    int l = idx >> 13;
    int r = idx & 8191;
    int j = r & 7;
    int lane = (r >> 3) & 63;
    int wt = r >> 9;
    int w = wt >> 2, t = wt & 3;
    int c = lane & 15, q = lane >> 4;
    int k = q * 8 + j;
    const float* Wf = (l == 0) ? Wf1 : (l == 1) ? Wf2 : Wf3;
    const float* Ws = (l == 0) ? Ws1 : (l == 1) ? Ws2 : Ws3;
    const float* W = (t < 2) ? Wf : Ws;
    int ch = w * 32 + 2 * c + (t & 1);
    wedge[(size_t)l * 8192 + r] = f2bf(W[(size_t)(256 + k) * 128 + ch] * LOG2E);
  } else if (b < 864) {
    // wgemm (x log2e): col cc -> T position p = (cc&~31) + 2*(cc&15) + ((cc>>4)&1)
    int idx = (b - 96) * 256 + tid;      // 3*65536
    int l = idx >> 16;
    int r = idx & 65535;
    int cc = r >> 7;
    int k = r & 127;
    int p = (cc & ~31) + ((cc & 15) << 1) + ((cc >> 4) & 1);
    int ph = p & 255;
    int j = ph >> 2, sub = ph & 3;
    const float* Wf = (l == 0) ? Wf1 : (l == 1) ? Wf2 : Wf3;
    const float* Ws = (l == 0) ? Ws1 : (l == 1) ? Ws2 : Ws3;
    const float* W = (sub < 2) ? Wf : Ws;
    int ch = 2 * j + (sub & 1);
    int krow = ((p < 256) ? 0 : 128) + k;
    wgemm[(size_t)l * 65536 + cc * 128 + k] = f2bf(W[(size_t)krow * 128 + ch] * LOG2E);
  } else if (b < 2114) {
    int e = (b - 864) * 256 + tid;       // NE
    atomicAdd(counts + ei[NE + e], 1);
  } else {
    int n = (b - 2114) * 256 + tid;
    if (n > NN) return;
    if (n == NN) {
      starts[NG] = NN;
      int last = batch[NN - 1];
      for (int g = last + 1; g < NG; ++g) starts[g] = NN;
    } else if (n == 0) {
      int bb = batch[0];
      for (int g = 0; g <= bb; ++g) starts[g] = 0;
    } else {
      int b0 = batch[n - 1], b1 = batch[n];
      for (int g = b0 + 1; g <= b1; ++g) starts[g] = n;
    }
  }
}

// exclusive prefix sum of counts[32000] -> offs
__global__ __launch_bounds__(1024) void k_scan(const int* __restrict__ counts,
                                               int* __restrict__ offs) {
  __shared__ int part[1024];
  __shared__ int carry_s;
  int t = threadIdx.x;
  if (t == 0) carry_s = 0;
  __syncthreads();
  for (int chunk = 0; chunk < 4; ++chunk) {
    int base = chunk * 8192 + t * 8;
    int4 a = make_int4(0, 0, 0, 0), bq = make_int4(0, 0, 0, 0);
    bool full = (base + 8 <= NN);
    if (full) {
      a = *(const int4*)(counts + base);
      bq = *(const int4*)(counts + base + 4);
    }
    int e1 = a.x, e2 = e1 + a.y, e3 = e2 + a.z, e4 = e3 + a.w;
    int e5 = e4 + bq.x, e6 = e5 + bq.y, e7 = e6 + bq.z;
    int run = e7 + bq.w;
    part[t] = run;
    __syncthreads();
    for (int off = 1; off < 1024; off <<= 1) {
      int v = (t >= off) ? part[t - off] : 0;
      __syncthreads();
      part[t] += v;
      __syncthreads();
    }
    int excl = carry_s + ((t == 0) ? 0 : part[t - 1]);
    if (full) {
      int4 o0 = make_int4(excl, excl + e1, excl + e2, excl + e3);
      int4 o1 = make_int4(excl + e4, excl + e5, excl + e6, excl + e7);
      *(int4*)(offs + base) = o0;
      *(int4*)(offs + base + 4) = o1;
    }
    __syncthreads();
    if (t == 0) carry_s += part[1023];
    __syncthreads();
  }
}

// scatter pass 1: perm[pos] = original edge index
__global__ __launch_bounds__(256) void k_scat1(const int* __restrict__ ei,
                                               int* __restrict__ offs,
                                               int* __restrict__ perm) {
  int e = blockIdx.x * 256 + threadIdx.x;
  int d = ei[NE + e];
  int pos = atomicAdd(offs + d, 1);
  perm[pos] = e;
}

// Merged dispatch: blocks 0..499 = embed + layer-1 GEMM (ugemm-style, 4 panels);
// blocks 500..5499 = scatter pass 2.
__global__ __launch_bounds__(256) void k_s2g(const int* __restrict__ x,
                                             const float* __restrict__ emb,
                                             const unsigned short* __restrict__ wgemmL,
                                             unsigned short* __restrict__ T,
                                             unsigned short* __restrict__ hb,
                                             unsigned short* __restrict__ accumb,
                                             const int* __restrict__ ei,
                                             const float* __restrict__ ea,
                                             const int* __restrict__ perm,
                                             int* __restrict__ srcp,
                                             int* __restrict__ dstp,
                                             unsigned short* __restrict__ eab) {
  __shared__ short sA[64 * 136];
  __shared__ short sB[128 * 136];
  __shared__ int se[64];
  int b = blockIdx.x;
  int tid = threadIdx.x;
  if (b < 500) {
    int m0 = b * 64;
    // embed 64 rows -> sA + hb (bf16); zero accumb. emb is 51KB (L2-resident).
#pragma unroll
    for (int i = 0; i < 4; ++i) {
      int idx = tid + i * 256;           // 0..1023
      int row = idx >> 4, c8 = (idx & 15) << 3;
      int n = m0 + row;
      const float* e = emb + (size_t)x[n] * 128 + c8;
      float4 v0 = *(const float4*)e;
      float4 v1 = *(const float4*)(e + 4);
      uint4 o;
      o.x = (unsigned)f2bf(v0.x) | ((unsigned)f2bf(v0.y) << 16);
      o.y = (unsigned)f2bf(v0.z) | ((unsigned)f2bf(v0.w) << 16);
      o.z = (unsigned)f2bf(v1.x) | ((unsigned)f2bf(v1.y) << 16);
      o.w = (unsigned)f2bf(v1.z) | ((unsigned)f2bf(v1.w) << 16);
      size_t off = (size_t)n * 128 + c8;
      *(uint4*)(hb + off) = o;
      *(uint4*)(accumb + off) = make_uint4(0, 0, 0, 0);
      *(uint4*)&sA[row * 136 + c8] = o;
    }
    int w = tid >> 6, lane = tid & 63, c = lane & 15, q = lane >> 4;
#pragma unroll 1
    for (int nb = 0; nb < 4; ++nb) {
      int n0 = nb * 128;
      __syncthreads();
#pragma unroll
      for (int i = 0; i < 8; ++i) {
        int idx = tid + i * 256;
        int col = idx >> 4, chk = idx & 15;
        uint4 v = *(const uint4*)(wgemmL + (size_t)(n0 + col) * 128 + chk * 8);
        *(uint4*)&sB[col * 136 + chk * 8] = v;
      }
      __syncthreads();
      frag_cd acc[4][2];
#pragma unroll
      for (int mt = 0; mt < 4; ++mt)
#pragma unroll
        for (int t = 0; t < 2; ++t) acc[mt][t] = (frag_cd){0.f, 0.f, 0.f, 0.f};
#pragma unroll
      for (int ks = 0; ks < 4; ++ks) {
        frag_ab Af[4], Bf[2];
#pragma unroll
        for (int mt = 0; mt < 4; ++mt)
          Af[mt] = *(const frag_ab*)&sA[(mt * 16 + c) * 136 + ks * 32 + q * 8];
#pragma unroll
        for (int t = 0; t < 2; ++t)
          Bf[t] = *(const frag_ab*)&sB[(w * 32 + t * 16 + c) * 136 + ks * 32 + q * 8];
#pragma unroll
        for (int mt = 0; mt < 4; ++mt)
#pragma unroll
          for (int t = 0; t < 2; ++t)
            acc[mt][t] = __builtin_amdgcn_mfma_f32_16x16x32_bf16(Af[mt], Bf[t], acc[mt][t], 0, 0, 0);
      }
      int nbase = n0 + w * 32 + 2 * c;
#pragma unroll
      for (int mt = 0; mt < 4; ++mt) {
#pragma unroll
        for (int r = 0; r < 4; ++r) {
          int node = m0 + mt * 16 + q * 4 + r;
          unsigned pk = (unsigned)f2bf(acc[mt][0][r]) | ((unsigned)f2bf(acc[mt][1][r]) << 16);
          *(unsigned*)(T + (size_t)node * 512 + nbase) = pk;
        }
      }
    }
  } else {
    int base = (b - 500) * 64;
    if (tid < 64) {
      int e = perm[base + tid];
      se[tid] = e;
      srcp[base + tid] = ei[e];
      dstp[base + tid] = ei[NE + e];
    }
    __syncthreads();
    int xs = tid >> 2;
    int ck = tid & 3;
    int e = se[xs];
    const float* a = ea + (size_t)e * 32 + ck * 8;
    float4 v0 = *(const float4*)a;
    float4 v1 = *(const float4*)(a + 4);
    int p = (((xs >> 2) & 3) << 4) | ((xs >> 4) << 2) | (xs & 3);
    unsigned short* q = eab + (size_t)(base + p) * 32 + ck * 8;
    ushort4 o0, o1;
    o0.x = f2bf(v0.x); o0.y = f2bf(v0.y); o0.z = f2bf(v0.z); o0.w = f2bf(v0.w);
    o1.x = f2bf(v1.x); o1.y = f2bf(v1.y); o1.z = f2bf(v1.z); o1.w = f2bf(v1.w);
    *(ushort4*)q = o0;
    *(ushort4*)(q + 4) = o1;
  }
}

// Fused update + GEMM (layers 2,3): block owns 64 rows exclusively.
__global__ __launch_bounds__(256) void k_ugemm(unsigned short* __restrict__ hb,
                                               unsigned short* __restrict__ accumb,
                                               const unsigned short* __restrict__ wgemmL,
                                               unsigned short* __restrict__ T) {
  __shared__ short sA[64 * 136];
  __shared__ short sB[128 * 136];
  int m0 = blockIdx.x * 64;
  int tid = threadIdx.x;
#pragma unroll
  for (int i = 0; i < 4; ++i) {
    int idx = tid + i * 256;
    int row = idx >> 4, chk = idx & 15;
    size_t off = (size_t)(m0 + row) * 128 + chk * 8;
    uint4 a = *(uint4*)(accumb + off);
    uint4 hv = *(uint4*)(hb + off);
    float r0 = fmaxf(bflo(hv.x) + bflo(a.x), 0.f);
    float r1 = fmaxf(bfhi(hv.x) + bfhi(a.x), 0.f);
    float r2 = fmaxf(bflo(hv.y) + bflo(a.y), 0.f);
    float r3 = fmaxf(bfhi(hv.y) + bfhi(a.y), 0.f);
    float r4 = fmaxf(bflo(hv.z) + bflo(a.z), 0.f);
    float r5 = fmaxf(bfhi(hv.z) + bfhi(a.z), 0.f);
    float r6 = fmaxf(bflo(hv.w) + bflo(a.w), 0.f);
    float r7 = fmaxf(bfhi(hv.w) + bfhi(a.w), 0.f);
    uint4 o;
    o.x = (unsigned)f2bf(r0) | ((unsigned)f2bf(r1) << 16);
    o.y = (unsigned)f2bf(r2) | ((unsigned)f2bf(r3) << 16);
    o.z = (unsigned)f2bf(r4) | ((unsigned)f2bf(r5) << 16);
    o.w = (unsigned)f2bf(r6) | ((unsigned)f2bf(r7) << 16);
    *(uint4*)(hb + off) = o;
    *(uint4*)(accumb + off) = make_uint4(0, 0, 0, 0);
    *(uint4*)&sA[row * 136 + chk * 8] = o;
  }
  int w = tid >> 6, lane = tid & 63, c = lane & 15, q = lane >> 4;
#pragma unroll 1
  for (int nb = 0; nb < 4; ++nb) {
    int n0 = nb * 128;
    __syncthreads();
#pragma unroll
    for (int i = 0; i < 8; ++i) {
      int idx = tid + i * 256;
      int col = idx >> 4, chk = idx & 15;
      uint4 v = *(const uint4*)(wgemmL + (size_t)(n0 + col) * 128 + chk * 8);
      *(uint4*)&sB[col * 136 + chk * 8] = v;
    }
    __syncthreads();
    frag_cd acc[4][2];
#pragma unroll
    for (int mt = 0; mt < 4; ++mt)
#pragma unroll
      for (int t = 0; t < 2; ++t) acc[mt][t] = (frag_cd){0.f, 0.f, 0.f, 0.f};
#pragma unroll
    for (int ks = 0; ks < 4; ++ks) {
      frag_ab Af[4], Bf[2];
#pragma unroll
      for (int mt = 0; mt < 4; ++mt)
        Af[mt] = *(const frag_ab*)&sA[(mt * 16 + c) * 136 + ks * 32 + q * 8];
#pragma unroll
      for (int t = 0; t < 2; ++t)
        Bf[t] = *(const frag_ab*)&sB[(w * 32 + t * 16 + c) * 136 + ks * 32 + q * 8];
#pragma unroll
      for (int mt = 0; mt < 4; ++mt)
#pragma unroll
        for (int t = 0; t < 2; ++t)
          acc[mt][t] = __builtin_amdgcn_mfma_f32_16x16x32_bf16(Af[mt], Bf[t], acc[mt][t], 0, 0, 0);
    }
    int nbase = n0 + w * 32 + 2 * c;
#pragma unroll
    for (int mt = 0; mt < 4; ++mt) {
#pragma unroll
      for (int r = 0; r < 4; ++r) {
        int node = m0 + mt * 16 + q * 4 + r;
        unsigned pk = (unsigned)f2bf(acc[mt][0][r]) | ((unsigned)f2bf(acc[mt][1][r]) << 16);
        *(unsigned*)(T + (size_t)node * 512 + nbase) = pk;
      }
    }
  }
}

// Per-edge MFMA + software-pipelined gather/epilogue + register run-merge +
// packed bf16 atomics. 512 threads / 128 edges per block. Bias in C-operand.
__global__ __launch_bounds__(512) void k_edge(const int* __restrict__ srcp,
                                              const int* __restrict__ dstp,
                                              const unsigned short* __restrict__ eab,
                                              const unsigned short* __restrict__ T,
                                              const unsigned short* __restrict__ wedgeL,
                                              const float* __restrict__ bf,
                                              const float* __restrict__ bs,
                                              unsigned short* __restrict__ accumb) {
  __shared__ short sA[128 * 40];
  __shared__ short sB[8192];
  __shared__ float sbf[128], sbs[128];
  __shared__ int sSrc[128], sDst[128];
  int tid = threadIdx.x;
  int e0 = blockIdx.x * 128;
  {
    int row = tid >> 2, qq = tid & 3;
    uint4 v = *(const uint4*)(eab + (size_t)e0 * 32 + tid * 8);
    *(uint4*)&sA[row * 40 + qq * 8] = v;
  }
#pragma unroll
  for (int i = 0; i < 2; ++i) {
    int idx = tid + i * 512;
    uint4 v = *(const uint4*)(wedgeL + idx * 8);
    *(uint4*)&sB[idx * 8] = v;
  }
  if (tid < 128) {
    sbf[tid] = bf[tid] * LOG2E;
    sbs[tid] = bs[tid] * LOG2E;
  } else if (tid < 256) {
    sSrc[tid - 128] = srcp[e0 + tid - 128] * 512 + 256;
  } else if (tid < 384) {
    sDst[tid - 256] = dstp[e0 + tid - 256] * 512;
  }
  __syncthreads();

  int wave = tid >> 6;
  int w = wave & 3;
  int eh = (wave >> 2) * 64;
  int lane = tid & 63;
  int c = lane & 15;
  int q = lane >> 4;

  int ch = w * 32 + 2 * c;
  int jo = ch * 2;
  v2f bfv = {sbf[ch], sbf[ch + 1]};
  v2f bsv = {sbs[ch], sbs[ch + 1]};

  frag_ab Af[4], Bf[4];
#pragma unroll
  for (int et = 0; et < 4; ++et)
    Af[et] = *(const frag_ab*)&sA[(eh + et * 16 + c) * 40 + q * 8];
#pragma unroll
  for (int t = 0; t < 4; ++t)
    Bf[t] = *(const frag_ab*)&sB[((w * 4 + t) * 64 + lane) * 8];

  frag_cd acc[4][4];
#pragma unroll
  for (int et = 0; et < 4; ++et) {
    acc[et][0] = (frag_cd){bfv.x, bfv.x, bfv.x, bfv.x};
    acc[et][1] = (frag_cd){bfv.y, bfv.y, bfv.y, bfv.y};
    acc[et][2] = (frag_cd){bsv.x, bsv.x, bsv.x, bsv.x};
    acc[et][3] = (frag_cd){bsv.y, bsv.y, bsv.y, bsv.y};
  }
#pragma unroll
  for (int et = 0; et < 4; ++et)
#pragma unroll
    for (int t = 0; t < 4; ++t)
      acc[et][t] = __builtin_amdgcn_mfma_f32_16x16x32_bf16(Af[et], Bf[t], acc[et][t], 0, 0, 0);

  int le0 = eh + q * 16;
  int prevd = sDst[le0];
  v2f av = {0.f, 0.f};

  uint2 dvb[2][4], svb[2][4];
#pragma unroll
  for (int i = 0; i < 4; ++i) {
    int e = le0 + i;
    dvb[0][i] = *(const uint2*)(T + sDst[e] + jo);
    svb[0][i] = *(const uint2*)(T + sSrc[e] + jo);
  }
#pragma unroll
  for (int g = 0; g < 4; ++g) {
    int cur = g & 1, nxt = cur ^ 1;
    if (g < 3) {
#pragma unroll
      for (int i = 0; i < 4; ++i) {
        int e = le0 + (g + 1) * 4 + i;
        dvb[nxt][i] = *(const uint2*)(T + sDst[e] + jo);
        svb[nxt][i] = *(const uint2*)(T + sSrc[e] + jo);
      }
    }
    v2f m[4];
#pragma unroll
    for (int i = 0; i < 4; ++i) {
      v2f xf = (v2f){acc[g][0][i], acc[g][1][i]} + unpk(dvb[cur][i].x) + unpk(svb[cur][i].x);
      v2f xs = (v2f){acc[g][2][i], acc[g][3][i]} + unpk(dvb[cur][i].y) + unpk(svb[cur][i].y);
      float g0 = __builtin_amdgcn_rcpf(1.f + __builtin_amdgcn_exp2f(-xf.x));
      float g1 = __builtin_amdgcn_rcpf(1.f + __builtin_amdgcn_exp2f(-xf.y));
      float sp0 = fmaxf(xs.x, 0.f) + __builtin_amdgcn_logf(1.f + __builtin_amdgcn_exp2f(-fabsf(xs.x)));
      float sp1 = fmaxf(xs.y, 0.f) + __builtin_amdgcn_logf(1.f + __builtin_amdgcn_exp2f(-fabsf(xs.y)));
      m[i] = (v2f){g0 * sp0, g1 * sp1};
    }
#pragma unroll
    for (int i = 0; i < 4; ++i) {
      int d = sDst[le0 + g * 4 + i];
      if (d != prevd) {
        v2f o = av * LN2;
        unsigned pk = (unsigned)f2bf(o.x) | ((unsigned)f2bf(o.y) << 16);
        unsigned short* p = accumb + (size_t)(prevd >> 2) + ch;
        asm volatile("global_atomic_pk_add_bf16 %0, %1, off" :: "v"(p), "v"(pk) : "memory");
        av = (v2f){0.f, 0.f};
        prevd = d;
      }
      av += m[i];
    }
  }
  {
    v2f o = av * LN2;
    unsigned pk = (unsigned)f2bf(o.x) | ((unsigned)f2bf(o.y) << 16);
    unsigned short* p = accumb + (size_t)(prevd >> 2) + ch;
    asm volatile("global_atomic_pk_add_bf16 %0, %1, off" :: "v"(p), "v"(pk) : "memory");
  }
}

// Fused layer-3 update + segmented mean-pool + final matmul
__global__ __launch_bounds__(128) void k_pool_final(const unsigned short* __restrict__ hb,
                                                    const unsigned short* __restrict__ accumb,
                                                    const int* __restrict__ starts,
                                                    const float* __restrict__ Wlin,
                                                    const float* __restrict__ blin,
                                                    float* __restrict__ out) {
  __shared__ float p[128];
  int g = blockIdx.x, c = threadIdx.x;
  int s0 = starts[g], s1 = starts[g + 1];
  float acc = 0.f;
  for (int n = s0; n < s1; ++n) {
    float hv = bfs(hb[(size_t)n * 128 + c]);
    float av = bfs(accumb[(size_t)n * 128 + c]);
    acc += fmaxf(hv + av, 0.f);
  }
  float inv = 1.f / fmaxf((float)(s1 - s0), 1.f);
  p[c] = acc * inv;
  __syncthreads();
  float o = blin[c];
#pragma unroll 8
  for (int k = 0; k < 128; ++k) o += p[k] * Wlin[k * 128 + c];
  out[(size_t)g * 128 + c] = o;
}

extern "C" void kernel_launch(void* const* d_in, const int* in_sizes, int n_in,
                              void* d_out, int out_size, void* d_ws, size_t ws_size,
                              hipStream_t stream) {
  const int* x = (const int*)d_in[0];
  const int* ei = (const int*)d_in[1];
  const float* ea = (const float*)d_in[2];
  const int* batch = (const int*)d_in[3];
  const float* emb = (const float*)d_in[4];
  const float* Wf[3] = {(const float*)d_in[5], (const float*)d_in[9], (const float*)d_in[13]};
  const float* bf[3] = {(const float*)d_in[6], (const float*)d_in[10], (const float*)d_in[14]};
  const float* Wsm[3] = {(const float*)d_in[7], (const float*)d_in[11], (const float*)d_in[15]};
  const float* bs[3] = {(const float*)d_in[8], (const float*)d_in[12], (const float*)d_in[16]};
  const float* Wlin = (const float*)d_in[17];
  const float* blin = (const float*)d_in[18];
  float* out = (float*)d_out;

  char* ws = (char*)d_ws;
  unsigned short* hb = (unsigned short*)ws;     ws += (size_t)NN * 128 * 2;
  unsigned short* accumb = (unsigned short*)ws; ws += (size_t)NN * 128 * 2;
  unsigned short* T = (unsigned short*)ws;      ws += (size_t)NN * 512 * 2;
  unsigned short* eab = (unsigned short*)ws;    ws += (size_t)NE * 32 * 2;
  unsigned short* wedge = (unsigned short*)ws;  ws += 3 * 8192 * 2;
  unsigned short* wgemm = (unsigned short*)ws;  ws += 3 * 65536 * 2;
  int* counts = (int*)ws;                       ws += (size_t)NN * 4;   // zeroed
  int* offs = (int*)ws;                         ws += (size_t)NN * 4;
  int* srcp = (int*)ws;                         ws += (size_t)NE * 4;
  int* dstp = (int*)ws;                         ws += (size_t)NE * 4;
  int* perm = (int*)ws;                         ws += (size_t)NE * 4;
  int* starts = (int*)ws;                       ws += (size_t)(NG + 1) * 4;

  hipMemsetAsync(counts, 0, (size_t)NN * 4, stream);
  k_prephist<<<2240, 256, 0, stream>>>(Wf[0], Wsm[0], Wf[1], Wsm[1], Wf[2], Wsm[2],
                                       ei, batch, wedge, wgemm, counts, starts);
  k_scan<<<1, 1024, 0, stream>>>(counts, offs);
  k_scat1<<<1250, 256, 0, stream>>>(ei, offs, perm);
  k_s2g<<<5500, 256, 0, stream>>>(x, emb, wgemm, T, hb, accumb, ei, ea, perm,
                                  srcp, dstp, eab);
  for (int l = 0; l < 3; ++l) {
    if (l > 0)
      k_ugemm<<<500, 256, 0, stream>>>(hb, accumb, wgemm + (size_t)l * 65536, T);
    k_edge<<<2500, 512, 0, stream>>>(srcp, dstp, eab, T, wedge + (size_t)l * 8192,
                                     bf[l], bs[l], accumb);
  }
  k_pool_final<<<1600, 128, 0, stream>>>(hb, accumb, starts, Wlin, blin, out);
}